// Round 3
// baseline (70801.062 us; speedup 1.0000x reference)
//
#include <hip/hip_runtime.h>
#include <math.h>

// Problem constants (fixed by setup_inputs)
#define NWG 256
#define NT  512
#define BB  64      // batch
#define TT  512     // seq len
#define HH  512     // hidden
#define RR  1024    // decode rows = B*S
#define HOR 64      // horizon
#define WST 520     // LDS weight row stride (floats); 520*4B is 16B-aligned

typedef float v2f __attribute__((ext_vector_type(2)));

// Persistent state in device globals (re-initialized every launch)
__device__ float g_h0[2][BB][HH];
__device__ float g_h1[2][BB][HH];
__device__ float g_c0[BB][HH];
__device__ float g_c1[BB][HH];
__device__ float g_H0[2][RR][HH];
__device__ float g_H1[2][RR][HH];
__device__ float g_C0[RR][HH];
__device__ float g_C1[RR][HH];
__device__ float g_u[RR];

__device__ __forceinline__ float sigf(float v) { return 1.0f / (1.0f + expf(-v)); }

__device__ __forceinline__ float cellupd(float iv, float fv, float gv, float ov, float& c) {
  c = sigf(fv) * c + sigf(iv) * tanhf(gv);
  return sigf(ov) * tanhf(c);
}

// Grid barrier: monotonically increasing counter, agent-scope release/acquire.
// LDS ~56KB -> 2 WG/CU capacity: 256 WGs co-reside with 2x slack (no exact-fit
// deadlock; R2's 128KB-LDS exact fit is the suspected hang).
__device__ __forceinline__ void gridbar(unsigned* cnt, unsigned& phase) {
  __syncthreads();
  phase += NWG;
  if (threadIdx.x == 0) {
    __hip_atomic_fetch_add(cnt, 1u, __ATOMIC_ACQ_REL, __HIP_MEMORY_SCOPE_AGENT);
    while (__hip_atomic_load(cnt, __ATOMIC_ACQUIRE, __HIP_MEMORY_SCOPE_AGENT) < phase)
      __builtin_amdgcn_s_sleep(2);
  }
  __syncthreads();
}

// Reduce 32 values across the 32-lane half-wave; lane ks ends with the fully
// reduced value of index ks. All array indices are compile-time constants.
__device__ __forceinline__ float bfly32(float (&v)[32], const int ks) {
  float a16[16];
#pragma unroll
  for (int j = 0; j < 16; ++j) {
    const float lo = v[j], hi = v[j + 16];
    const float send = (ks & 16) ? lo : hi;
    const float recv = __shfl_xor(send, 16);
    a16[j] = ((ks & 16) ? hi : lo) + recv;
  }
  float a8[8];
#pragma unroll
  for (int j = 0; j < 8; ++j) {
    const float lo = a16[j], hi = a16[j + 8];
    const float send = (ks & 8) ? lo : hi;
    const float recv = __shfl_xor(send, 8);
    a8[j] = ((ks & 8) ? hi : lo) + recv;
  }
  float a4[4];
#pragma unroll
  for (int j = 0; j < 4; ++j) {
    const float lo = a8[j], hi = a8[j + 4];
    const float send = (ks & 4) ? lo : hi;
    const float recv = __shfl_xor(send, 4);
    a4[j] = ((ks & 4) ? hi : lo) + recv;
  }
  float a2[2];
#pragma unroll
  for (int j = 0; j < 2; ++j) {
    const float lo = a4[j], hi = a4[j + 2];
    const float send = (ks & 2) ? lo : hi;
    const float recv = __shfl_xor(send, 2);
    a2[j] = ((ks & 2) ? hi : lo) + recv;
  }
  const float lo = a2[0], hi = a2[1];
  const float send = (ks & 1) ? lo : hi;
  const float recv = __shfl_xor(send, 1);
  return ((ks & 1) ? hi : lo) + recv;
}

__global__ __launch_bounds__(NT, 4) void lstm_all(
    const float* __restrict__ x, const float* __restrict__ init_input,
    const float* __restrict__ w_ih0, const float* __restrict__ w_hh0,
    const float* __restrict__ b0, const float* __restrict__ w_ih1,
    const float* __restrict__ w_hh1, const float* __restrict__ b1,
    const float* __restrict__ w_out, const float* __restrict__ b_out,
    float* __restrict__ out, unsigned* cnt) {
  const int wg = blockIdx.x;
  const int tid = threadIdx.x;
  const int jh0 = wg * 2;  // this WG owns hidden cols jh0, jh0+1 (x4 gates)

  // weight rows, gate-major: row r8 = gate*2+q  -> w[gate*HH + jh0 + q][:]
  __shared__ __align__(16) float s_whh0[8 * WST];
  __shared__ __align__(16) float s_wih1[8 * WST];
  __shared__ __align__(16) float s_whh1[8 * WST];
  __shared__ __align__(16) float s_gb0[64 * 8];  // gate exchange L0 [b][q][gate]
  __shared__ __align__(16) float s_gb1[64 * 8];  // gate exchange L1
  __shared__ __align__(16) float s_wout[HH];
  __shared__ float s_wih0[8], s_b0[8], s_b1[8];
  __shared__ float s_red[8];

  // ---- load persistent weight rows into LDS ----
  for (int r8 = 0; r8 < 8; ++r8) {
    int gate = r8 >> 1, q = r8 & 1;
    int j = gate * HH + jh0 + q;
    s_whh0[r8 * WST + tid] = w_hh0[j * HH + tid];
    s_wih1[r8 * WST + tid] = w_ih1[j * HH + tid];
    s_whh1[r8 * WST + tid] = w_hh1[j * HH + tid];
  }
  if (tid < 8) {
    int gate = tid >> 1, q = tid & 1;
    int j = gate * HH + jh0 + q;
    s_wih0[tid] = w_ih0[j];
    s_b0[tid] = b0[j];
    s_b1[tid] = b1[j];
  }
  s_wout[tid] = w_out[tid];

  // ---- zero-init encoder state ----
  {
    int idx = wg * NT + tid;
    if (idx < 2 * BB * HH) {
      (&g_h0[0][0][0])[idx] = 0.f;
      (&g_h1[0][0][0])[idx] = 0.f;
    }
    if (idx < BB * HH) {
      (&g_c0[0][0])[idx] = 0.f;
      (&g_c1[0][0])[idx] = 0.f;
    }
  }
  unsigned phase = 0;
  gridbar(cnt, phase);

  // =========================== ENCODER ===========================
  // thread tile: 4 rows x 8 gate-rows per layer, K-split 32 (16 k-el each,
  // k = ks*4 + j*128). L0 (tick tk) + L1 (tick tk-1) fused: single pass over
  // g_h0[cur]; in-wave butterfly replaces the LDS partial-reduce.
  const int rg = tid >> 5;
  const int ks = tid & 31;
  const int eb = rg * 4 + (ks >> 3);   // butterfly output: batch row
  const int eg2 = ks & 7;              // butterfly output: gate*2+q
  const int eslot = eb * 8 + ((eg2 & 1) << 2) + (eg2 >> 1);

  for (int tk = 1; tk <= TT + 1; ++tk) {
    const int cur = (tk - 1) & 1, nxt = tk & 1;
    const bool do0 = (tk <= TT), do1 = (tk >= 2);
    float acc0[32], acc1[32];
#pragma unroll
    for (int v = 0; v < 32; ++v) { acc0[v] = 0.f; acc1[v] = 0.f; }
    const int b0r = rg * 4;
#pragma unroll
    for (int j = 0; j < 4; ++j) {
      const int k = ks * 4 + j * 128;
      float4 hv[4];
#pragma unroll
      for (int r = 0; r < 4; ++r) hv[r] = *(const float4*)&g_h0[cur][b0r + r][k];
      if (do0) {
#pragma unroll
        for (int g = 0; g < 8; ++g) {
          const float4 wv = *(const float4*)&s_whh0[g * WST + k];
#pragma unroll
          for (int r = 0; r < 4; ++r) {
            acc0[r * 8 + g] = fmaf(hv[r].x, wv.x, acc0[r * 8 + g]);
            acc0[r * 8 + g] = fmaf(hv[r].y, wv.y, acc0[r * 8 + g]);
            acc0[r * 8 + g] = fmaf(hv[r].z, wv.z, acc0[r * 8 + g]);
            acc0[r * 8 + g] = fmaf(hv[r].w, wv.w, acc0[r * 8 + g]);
          }
        }
      }
      if (do1) {
#pragma unroll
        for (int g = 0; g < 8; ++g) {
          const float4 wv = *(const float4*)&s_wih1[g * WST + k];
#pragma unroll
          for (int r = 0; r < 4; ++r) {
            acc1[r * 8 + g] = fmaf(hv[r].x, wv.x, acc1[r * 8 + g]);
            acc1[r * 8 + g] = fmaf(hv[r].y, wv.y, acc1[r * 8 + g]);
            acc1[r * 8 + g] = fmaf(hv[r].z, wv.z, acc1[r * 8 + g]);
            acc1[r * 8 + g] = fmaf(hv[r].w, wv.w, acc1[r * 8 + g]);
          }
        }
        float4 h1v[4];
#pragma unroll
        for (int r = 0; r < 4; ++r) h1v[r] = *(const float4*)&g_h1[nxt][b0r + r][k];
#pragma unroll
        for (int g = 0; g < 8; ++g) {
          const float4 wv = *(const float4*)&s_whh1[g * WST + k];
#pragma unroll
          for (int r = 0; r < 4; ++r) {
            acc1[r * 8 + g] = fmaf(h1v[r].x, wv.x, acc1[r * 8 + g]);
            acc1[r * 8 + g] = fmaf(h1v[r].y, wv.y, acc1[r * 8 + g]);
            acc1[r * 8 + g] = fmaf(h1v[r].z, wv.z, acc1[r * 8 + g]);
            acc1[r * 8 + g] = fmaf(h1v[r].w, wv.w, acc1[r * 8 + g]);
          }
        }
      }
    }
    if (do0) {
      float v0 = bfly32(acc0, ks);
      v0 += x[eb * TT + (tk - 1)] * s_wih0[eg2] + s_b0[eg2];
      s_gb0[eslot] = v0;
    }
    if (do1) {
      s_gb1[eslot] = bfly32(acc1, ks) + s_b1[eg2];
    }
    __syncthreads();
    if (do0 && tid < 128) {  // cell0 -> h0^{tk}
      const int b = tid >> 1, q = tid & 1, jh = jh0 + q;
      const float4 gv = *(const float4*)&s_gb0[(b << 3) + (q << 2)];
      float c = g_c0[b][jh];
      g_h0[nxt][b][jh] = cellupd(gv.x, gv.y, gv.z, gv.w, c);
      g_c0[b][jh] = c;
    }
    if (do1 && tid >= 128 && tid < 256) {  // cell1 -> h1^{tk-1}
      const int t = tid - 128, b = t >> 1, q = t & 1, jh = jh0 + q;
      const float4 gv = *(const float4*)&s_gb1[(b << 3) + (q << 2)];
      float c = g_c1[b][jh];
      g_h1[cur][b][jh] = cellupd(gv.x, gv.y, gv.z, gv.w, c);
      g_c1[b][jh] = c;
    }
    gridbar(cnt, phase);
  }

  // ---- expand final states over n_samples: row r = b*16+s ----
  {
    int gt = wg * NT + tid;          // 0..131071 == RR*HH/4 float4 slots
    int r = gt >> 7, k4 = gt & 127;  // HH/4 = 128
    int b = r >> 4;
    ((float4*)&g_H0[0][r][0])[k4] = ((const float4*)&g_h0[0][b][0])[k4];
    ((float4*)&g_C0[r][0])[k4] = ((const float4*)&g_c0[b][0])[k4];
    ((float4*)&g_H1[0][r][0])[k4] = ((const float4*)&g_h1[0][b][0])[k4];
    ((float4*)&g_C1[r][0])[k4] = ((const float4*)&g_c1[b][0])[k4];
    if (gt < RR) g_u[gt] = init_input[gt];
  }
  gridbar(cnt, phase);

  // =========================== DECODER ===========================
  // thread tile: 1 gate-row x 16 rows (rows rl + 64*m). Gate exchange via
  // in-wave shuffles (xor 2/4/6 within each 8-lane group); gate-0 lanes
  // (g2q<2) apply the cell update for their q column.
  const int g2q = tid & 7;   // gate*2+q
  const int rl = tid >> 3;   // 0..63

  for (int d = 0; d < HOR; ++d) {
    const int cur = d & 1, nxt = cur ^ 1;

    // ---- L0 ----
    {
      v2f acc[16];
#pragma unroll
      for (int m = 0; m < 16; ++m) acc[m] = (v2f){0.f, 0.f};
      const float* wrow = &s_whh0[g2q * WST];
      const float* hb = &g_H0[cur][0][0] + rl * HH;
      for (int k4 = 0; k4 < 128; ++k4) {
        const float4 wv = *(const float4*)(wrow + k4 * 4);
        const v2f wa = {wv.x, wv.y}, wb = {wv.z, wv.w};
        const float* hp = hb + k4 * 4;
#pragma unroll
        for (int m = 0; m < 16; ++m) {
          const float4 hv = *(const float4*)(hp + m * 64 * HH);
          const v2f ha = {hv.x, hv.y}, hc = {hv.z, hv.w};
          acc[m] = __builtin_elementwise_fma(ha, wa, acc[m]);
          acc[m] = __builtin_elementwise_fma(hc, wb, acc[m]);
        }
      }
      const float w0 = s_wih0[g2q], bb = s_b0[g2q];
      float val[16], fv[16], gv[16], ov[16];
#pragma unroll
      for (int m = 0; m < 16; ++m) {
        const int r = rl + m * 64;
        val[m] = acc[m].x + acc[m].y + g_u[r] * w0 + bb;
      }
#pragma unroll
      for (int m = 0; m < 16; ++m) {
        fv[m] = __shfl_xor(val[m], 2);
        gv[m] = __shfl_xor(val[m], 4);
        ov[m] = __shfl_xor(val[m], 6);
      }
      if (g2q < 2) {
        const int q = g2q, jh = jh0 + q;
#pragma unroll
        for (int m = 0; m < 16; ++m) {
          const int r = rl + m * 64;
          float c = g_C0[r][jh];
          g_H0[nxt][r][jh] = cellupd(val[m], fv[m], gv[m], ov[m], c);
          g_C0[r][jh] = c;
        }
      }
    }
    gridbar(cnt, phase);

    // ---- L1 ----
    {
      v2f acc[16];
#pragma unroll
      for (int m = 0; m < 16; ++m) acc[m] = (v2f){0.f, 0.f};
      const float* w1 = &s_wih1[g2q * WST];
      const float* w2 = &s_whh1[g2q * WST];
      const float* ha = &g_H0[nxt][0][0] + rl * HH;
      const float* hb1 = &g_H1[cur][0][0] + rl * HH;
      for (int k4 = 0; k4 < 128; ++k4) {
        const float4 wv1 = *(const float4*)(w1 + k4 * 4);
        const float4 wv2 = *(const float4*)(w2 + k4 * 4);
        const v2f wa1 = {wv1.x, wv1.y}, wb1 = {wv1.z, wv1.w};
        const v2f wa2 = {wv2.x, wv2.y}, wb2 = {wv2.z, wv2.w};
        const float* hpa = ha + k4 * 4;
        const float* hpb = hb1 + k4 * 4;
#pragma unroll
        for (int m = 0; m < 16; ++m) {
          const float4 av = *(const float4*)(hpa + m * 64 * HH);
          const float4 bv = *(const float4*)(hpb + m * 64 * HH);
          const v2f a1 = {av.x, av.y}, a2 = {av.z, av.w};
          const v2f b1v = {bv.x, bv.y}, b2v = {bv.z, bv.w};
          acc[m] = __builtin_elementwise_fma(a1, wa1, acc[m]);
          acc[m] = __builtin_elementwise_fma(a2, wb1, acc[m]);
          acc[m] = __builtin_elementwise_fma(b1v, wa2, acc[m]);
          acc[m] = __builtin_elementwise_fma(b2v, wb2, acc[m]);
        }
      }
      const float bb = s_b1[g2q];
      float val[16], fv[16], gv[16], ov[16];
#pragma unroll
      for (int m = 0; m < 16; ++m) val[m] = acc[m].x + acc[m].y + bb;
#pragma unroll
      for (int m = 0; m < 16; ++m) {
        fv[m] = __shfl_xor(val[m], 2);
        gv[m] = __shfl_xor(val[m], 4);
        ov[m] = __shfl_xor(val[m], 6);
      }
      if (g2q < 2) {
        const int q = g2q, jh = jh0 + q;
#pragma unroll
        for (int m = 0; m < 16; ++m) {
          const int r = rl + m * 64;
          float c = g_C1[r][jh];
          g_H1[nxt][r][jh] = cellupd(val[m], fv[m], gv[m], ov[m], c);
          g_C1[r][jh] = c;
        }
      }
    }
    gridbar(cnt, phase);

    // ---- pred: u = H1[nxt] . w_out + b_out ; out[r][d] = u ----
    {
      const int r = wg * 4 + (tid >> 7);
      const int p = tid & 127;
      const float4* hp = (const float4*)&g_H1[nxt][r][0];
      const float4* wo = (const float4*)s_wout;
      const float4 a = hp[p], w4 = wo[p];
      float pv = a.x * w4.x + a.y * w4.y + a.z * w4.z + a.w * w4.w;
      for (int off = 32; off; off >>= 1) pv += __shfl_down(pv, off);
      if ((tid & 63) == 0) s_red[tid >> 6] = pv;
      __syncthreads();
      if (p == 0) {
        const float tot = s_red[(tid >> 7) * 2] + s_red[(tid >> 7) * 2 + 1] + b_out[0];
        g_u[r] = tot;
        out[r * HOR + d] = tot;
      }
    }
    gridbar(cnt, phase);
  }
}

extern "C" void kernel_launch(void* const* d_in, const int* in_sizes, int n_in,
                              void* d_out, int out_size, void* d_ws, size_t ws_size,
                              hipStream_t stream) {
  (void)in_sizes; (void)n_in; (void)out_size; (void)ws_size;
  hipMemsetAsync(d_ws, 0, 256, stream);
  lstm_all<<<NWG, NT, 0, stream>>>(
      (const float*)d_in[0], (const float*)d_in[1], (const float*)d_in[2],
      (const float*)d_in[3], (const float*)d_in[4], (const float*)d_in[5],
      (const float*)d_in[6], (const float*)d_in[7], (const float*)d_in[8],
      (const float*)d_in[9], (float*)d_out, (unsigned*)d_ws);
}

// Round 5
// 40031.747 us; speedup vs baseline: 1.7686x; 1.7686x over previous
//
#include <hip/hip_runtime.h>
#include <math.h>

// Problem constants (fixed by setup_inputs)
#define NWG 256
#define NT  512
#define BB  64      // batch
#define TT  512     // seq len
#define HH  512     // hidden
#define RR  1024    // decode rows = B*S
#define HOR 64      // horizon
#define WST 520     // LDS weight row stride (floats)

typedef float v2f __attribute__((ext_vector_type(2)));

// Persistent state in device globals (re-initialized every launch)
__device__ float g_h0[2][BB][HH];
__device__ float g_h1[2][BB][HH];
__device__ float g_c0[BB][HH];
__device__ float g_c1[BB][HH];
__device__ float g_H0[2][RR][HH];
__device__ float g_H1[2][RR][HH];
__device__ float g_C0[RR][HH];
__device__ float g_C1[RR][HH];
__device__ float g_u[RR];

__device__ __forceinline__ float sigf(float v) { return 1.0f / (1.0f + expf(-v)); }

__device__ __forceinline__ float cellupd(float iv, float fv, float gv, float ov, float& c) {
  c = sigf(fv) * c + sigf(iv) * tanhf(gv);
  return sigf(ov) * tanhf(c);
}

// Grid barrier (encoder only). SAFETY RULE (hangs R2,R4): every resource
// (LDS, VGPR via __launch_bounds__(512,4)) must guarantee >=2 WG/CU so the
// 256-WG co-residency has 2x slack. Do NOT raise the VGPR cap.
__device__ __forceinline__ void gridbar(unsigned* cnt, unsigned& phase) {
  __syncthreads();
  phase += NWG;
  if (threadIdx.x == 0) {
    __hip_atomic_fetch_add(cnt, 1u, __ATOMIC_ACQ_REL, __HIP_MEMORY_SCOPE_AGENT);
    while (__hip_atomic_load(cnt, __ATOMIC_ACQUIRE, __HIP_MEMORY_SCOPE_AGENT) < phase)
      __builtin_amdgcn_s_sleep(2);
  }
  __syncthreads();
}

// Reduce 16 values across a 16-lane group; lane ksl ends with reduced value
// of index ksl. Same scheme as the HW-verified bfly32 (R3, absmax=0).
__device__ __forceinline__ float bfly16(float (&v)[16], const int ksl) {
  float a8[8];
#pragma unroll
  for (int j = 0; j < 8; ++j) {
    const float lo = v[j], hi = v[j + 8];
    const float send = (ksl & 8) ? lo : hi;
    const float recv = __shfl_xor(send, 8);
    a8[j] = ((ksl & 8) ? hi : lo) + recv;
  }
  float a4[4];
#pragma unroll
  for (int j = 0; j < 4; ++j) {
    const float lo = a8[j], hi = a8[j + 4];
    const float send = (ksl & 4) ? lo : hi;
    const float recv = __shfl_xor(send, 4);
    a4[j] = ((ksl & 4) ? hi : lo) + recv;
  }
  float a2[2];
#pragma unroll
  for (int j = 0; j < 2; ++j) {
    const float lo = a4[j], hi = a4[j + 2];
    const float send = (ksl & 2) ? lo : hi;
    const float recv = __shfl_xor(send, 2);
    a2[j] = ((ksl & 2) ? hi : lo) + recv;
  }
  const float lo = a2[0], hi = a2[1];
  const float send = (ksl & 1) ? lo : hi;
  const float recv = __shfl_xor(send, 1);
  return ((ksl & 1) ? hi : lo) + recv;
}

// ======================= ENCODER (persistent) =======================
// 256 WGs x 512 thr. WG owns h-cols jh0, jh0+1 (8 gate-rows per matrix).
// Thread tile: 2 batch-rows x 8 gate-rows, K-split 16 (32 k-els/thread,
// k = ksl*4 + j*64). acc[16] only -> ~50 live floats, no spill at cap 128.
__global__ __launch_bounds__(NT, 4) void enc_kernel(
    const float* __restrict__ x, const float* __restrict__ init_input,
    const float* __restrict__ w_ih0, const float* __restrict__ w_hh0,
    const float* __restrict__ b0, const float* __restrict__ w_ih1,
    const float* __restrict__ w_hh1, const float* __restrict__ b1,
    unsigned* cnt) {
  const int wg = blockIdx.x;
  const int tid = threadIdx.x;
  const int jh0 = wg * 2;

  __shared__ __align__(16) float s_whh0[8 * WST];
  __shared__ __align__(16) float s_wih1[8 * WST];
  __shared__ __align__(16) float s_whh1[8 * WST];
  __shared__ __align__(16) float s_gb0[64 * 8];  // [b][q][gate]
  __shared__ __align__(16) float s_gb1[64 * 8];
  __shared__ float s_wih0[8], s_b0[8], s_b1[8];

  for (int r8 = 0; r8 < 8; ++r8) {
    int gate = r8 >> 1, q = r8 & 1;
    int j = gate * HH + jh0 + q;
    s_whh0[r8 * WST + tid] = w_hh0[j * HH + tid];
    s_wih1[r8 * WST + tid] = w_ih1[j * HH + tid];
    s_whh1[r8 * WST + tid] = w_hh1[j * HH + tid];
  }
  if (tid < 8) {
    int gate = tid >> 1, q = tid & 1;
    int j = gate * HH + jh0 + q;
    s_wih0[tid] = w_ih0[j];
    s_b0[tid] = b0[j];
    s_b1[tid] = b1[j];
  }
  {  // zero-init encoder state
    int idx = wg * NT + tid;
    if (idx < 2 * BB * HH) {
      (&g_h0[0][0][0])[idx] = 0.f;
      (&g_h1[0][0][0])[idx] = 0.f;
    }
    if (idx < BB * HH) {
      (&g_c0[0][0])[idx] = 0.f;
      (&g_c1[0][0])[idx] = 0.f;
    }
  }
  unsigned phase = 0;
  gridbar(cnt, phase);

  const int grp = tid >> 4;          // 32 row-groups -> rows grp*2, grp*2+1
  const int ksl = tid & 15;          // K-split 16: k = ksl*4 + j*64
  const int b0r = grp * 2;
  const int eb = b0r + (ksl >> 3);   // butterfly output: batch row
  const int r8o = ksl & 7;           // butterfly output: gate-row (gate*2+q)
  const int eslot = eb * 8 + ((r8o & 1) << 2) + (r8o >> 1);

  for (int tk = 1; tk <= TT + 1; ++tk) {
    const int cur = (tk - 1) & 1, nxt = tk & 1;

    if (tk <= TT) {  // ---- L0 matmul: gates0 = h0[cur] @ whh0^T ----
      float acc[16];
#pragma unroll
      for (int v = 0; v < 16; ++v) acc[v] = 0.f;
#pragma unroll
      for (int j = 0; j < 8; ++j) {
        const int k = ksl * 4 + j * 64;
        float4 hv[2];
#pragma unroll
        for (int r = 0; r < 2; ++r) hv[r] = *(const float4*)&g_h0[cur][b0r + r][k];
#pragma unroll
        for (int g = 0; g < 8; ++g) {
          const float4 wv = *(const float4*)&s_whh0[g * WST + k];
#pragma unroll
          for (int r = 0; r < 2; ++r) {
            acc[r * 8 + g] = fmaf(hv[r].x, wv.x, acc[r * 8 + g]);
            acc[r * 8 + g] = fmaf(hv[r].y, wv.y, acc[r * 8 + g]);
            acc[r * 8 + g] = fmaf(hv[r].z, wv.z, acc[r * 8 + g]);
            acc[r * 8 + g] = fmaf(hv[r].w, wv.w, acc[r * 8 + g]);
          }
        }
      }
      float v0 = bfly16(acc, ksl);
      v0 += x[eb * TT + (tk - 1)] * s_wih0[r8o] + s_b0[r8o];
      s_gb0[eslot] = v0;
    }

    if (tk >= 2) {  // ---- L1: gates1 = h0[cur] @ wih1^T + h1^{tk-2} @ whh1^T ----
      float acc[16];
#pragma unroll
      for (int v = 0; v < 16; ++v) acc[v] = 0.f;
#pragma unroll
      for (int j = 0; j < 8; ++j) {
        const int k = ksl * 4 + j * 64;
        float4 hv[2];
#pragma unroll
        for (int r = 0; r < 2; ++r) hv[r] = *(const float4*)&g_h0[cur][b0r + r][k];
#pragma unroll
        for (int g = 0; g < 8; ++g) {
          const float4 wv = *(const float4*)&s_wih1[g * WST + k];
#pragma unroll
          for (int r = 0; r < 2; ++r) {
            acc[r * 8 + g] = fmaf(hv[r].x, wv.x, acc[r * 8 + g]);
            acc[r * 8 + g] = fmaf(hv[r].y, wv.y, acc[r * 8 + g]);
            acc[r * 8 + g] = fmaf(hv[r].z, wv.z, acc[r * 8 + g]);
            acc[r * 8 + g] = fmaf(hv[r].w, wv.w, acc[r * 8 + g]);
          }
        }
#pragma unroll
        for (int r = 0; r < 2; ++r) hv[r] = *(const float4*)&g_h1[nxt][b0r + r][k];
#pragma unroll
        for (int g = 0; g < 8; ++g) {
          const float4 wv = *(const float4*)&s_whh1[g * WST + k];
#pragma unroll
          for (int r = 0; r < 2; ++r) {
            acc[r * 8 + g] = fmaf(hv[r].x, wv.x, acc[r * 8 + g]);
            acc[r * 8 + g] = fmaf(hv[r].y, wv.y, acc[r * 8 + g]);
            acc[r * 8 + g] = fmaf(hv[r].z, wv.z, acc[r * 8 + g]);
            acc[r * 8 + g] = fmaf(hv[r].w, wv.w, acc[r * 8 + g]);
          }
        }
      }
      s_gb1[eslot] = bfly16(acc, ksl) + s_b1[r8o];
    }
    __syncthreads();

    if (tk <= TT && tid < 128) {  // cell0 -> h0^{tk}
      const int b = tid >> 1, q = tid & 1, jh = jh0 + q;
      const float4 gv = *(const float4*)&s_gb0[(b << 3) + (q << 2)];
      float c = g_c0[b][jh];
      g_h0[nxt][b][jh] = cellupd(gv.x, gv.y, gv.z, gv.w, c);
      g_c0[b][jh] = c;
    }
    if (tk >= 2 && tid >= 128 && tid < 256) {  // cell1 -> h1^{tk-1}
      const int t = tid - 128, b = t >> 1, q = t & 1, jh = jh0 + q;
      const float4 gv = *(const float4*)&s_gb1[(b << 3) + (q << 2)];
      float c = g_c1[b][jh];
      g_h1[cur][b][jh] = cellupd(gv.x, gv.y, gv.z, gv.w, c);
      g_c1[b][jh] = c;
    }
    gridbar(cnt, phase);
  }

  // ---- expand final states over n_samples: row r = b*16+s ----
  {
    int gt = wg * NT + tid;          // 0..131071 == RR*HH/4 float4 slots
    int r = gt >> 7, k4 = gt & 127;
    int b = r >> 4;
    ((float4*)&g_H0[0][r][0])[k4] = ((const float4*)&g_h0[0][b][0])[k4];
    ((float4*)&g_C0[r][0])[k4] = ((const float4*)&g_c0[b][0])[k4];
    ((float4*)&g_H1[0][r][0])[k4] = ((const float4*)&g_h1[0][b][0])[k4];
    ((float4*)&g_C1[r][0])[k4] = ((const float4*)&g_c1[b][0])[k4];
    if (gt < RR) g_u[gt] = init_input[gt];
  }
}

// ======================= DECODER (per-step kernels) =======================
// No grid barriers: kernel boundaries are the global sync (cannot deadlock).
// Grid 1024 WGs x 256 thr. WG = (CG = bid&127 -> h-cols CG*4..+3,
// RQ = bid>>7 -> rows RQ*128..+127). Thread: g16 = gate*4+qc, rl; 8 rows.
// Gate exchange via shfl_xor 4/8/12 inside the 16-lane group.

__global__ __launch_bounds__(256, 4) void dec_l0(
    const float* __restrict__ w_hh0, const float* __restrict__ w_ih0,
    const float* __restrict__ b0, int d) {
  __shared__ __align__(16) float s_w[16 * WST];
  __shared__ float s_wi[16], s_b[16];
  const int tid = threadIdx.x;
  const int CG = blockIdx.x & 127, RQ = blockIdx.x >> 7;
  const int g16 = tid & 15, rl = tid >> 4;

  for (int i = tid; i < 16 * HH; i += 256) {
    const int r16 = i >> 9, k = i & 511;
    const int j = (r16 >> 2) * HH + CG * 4 + (r16 & 3);
    s_w[r16 * WST + k] = w_hh0[j * HH + k];
  }
  if (tid < 16) {
    const int j = (tid >> 2) * HH + CG * 4 + (tid & 3);
    s_wi[tid] = w_ih0[j];
    s_b[tid] = b0[j];
  }
  __syncthreads();

  const int cur = d & 1, nxt = cur ^ 1;
  const int rr0 = RQ * 128 + rl;
  float ureg[8];
#pragma unroll
  for (int m = 0; m < 8; ++m) ureg[m] = g_u[rr0 + 16 * m];

  v2f acc[8];
#pragma unroll
  for (int m = 0; m < 8; ++m) acc[m] = (v2f){0.f, 0.f};
  const float* wrow = &s_w[g16 * WST];
  const float* Hb = &g_H0[cur][0][0] + rr0 * HH;
  for (int k4 = 0; k4 < 128; ++k4) {
    const float4 wv = *(const float4*)(wrow + k4 * 4);
    const v2f wa = {wv.x, wv.y}, wb = {wv.z, wv.w};
    const float* hp = Hb + k4 * 4;
#pragma unroll
    for (int m = 0; m < 8; ++m) {
      const float4 hv = *(const float4*)(hp + m * 16 * HH);
      const v2f h1 = {hv.x, hv.y}, h2 = {hv.z, hv.w};
      acc[m] = __builtin_elementwise_fma(h1, wa, acc[m]);
      acc[m] = __builtin_elementwise_fma(h2, wb, acc[m]);
    }
  }
  const float wi = s_wi[g16], bb = s_b[g16];
#pragma unroll
  for (int m = 0; m < 8; ++m) {
    const int rr = rr0 + 16 * m;
    const float val = acc[m].x + acc[m].y + ureg[m] * wi + bb;
    const float fv = __shfl_xor(val, 4);
    const float gv = __shfl_xor(val, 8);
    const float ov = __shfl_xor(val, 12);
    if (g16 < 4) {  // gate==0 lanes own column qc=g16
      const int jc = CG * 4 + g16;
      float c = g_C0[rr][jc];
      g_H0[nxt][rr][jc] = cellupd(val, fv, gv, ov, c);
      g_C0[rr][jc] = c;
    }
  }
}

__global__ __launch_bounds__(256, 4) void dec_l1(
    const float* __restrict__ w_ih1, const float* __restrict__ w_hh1,
    const float* __restrict__ b1, int d) {
  __shared__ __align__(16) float s_w1[16 * WST];
  __shared__ __align__(16) float s_w2[16 * WST];
  __shared__ float s_b[16];
  const int tid = threadIdx.x;
  const int CG = blockIdx.x & 127, RQ = blockIdx.x >> 7;
  const int g16 = tid & 15, rl = tid >> 4;

  for (int i = tid; i < 16 * HH; i += 256) {
    const int r16 = i >> 9, k = i & 511;
    const int j = (r16 >> 2) * HH + CG * 4 + (r16 & 3);
    s_w1[r16 * WST + k] = w_ih1[j * HH + k];
    s_w2[r16 * WST + k] = w_hh1[j * HH + k];
  }
  if (tid < 16) {
    const int j = (tid >> 2) * HH + CG * 4 + (tid & 3);
    s_b[tid] = b1[j];
  }
  __syncthreads();

  const int cur = d & 1, nxt = cur ^ 1;
  const int rr0 = RQ * 128 + rl;

  v2f acc[8];
#pragma unroll
  for (int m = 0; m < 8; ++m) acc[m] = (v2f){0.f, 0.f};
  const float* w1r = &s_w1[g16 * WST];
  const float* w2r = &s_w2[g16 * WST];
  const float* Ha = &g_H0[nxt][0][0] + rr0 * HH;  // h0^{d+1}
  const float* Hb = &g_H1[cur][0][0] + rr0 * HH;  // h1^{d}
  for (int k4 = 0; k4 < 128; ++k4) {
    const float4 wv1 = *(const float4*)(w1r + k4 * 4);
    const float4 wv2 = *(const float4*)(w2r + k4 * 4);
    const v2f wa1 = {wv1.x, wv1.y}, wb1 = {wv1.z, wv1.w};
    const v2f wa2 = {wv2.x, wv2.y}, wb2 = {wv2.z, wv2.w};
    const float* hpa = Ha + k4 * 4;
    const float* hpb = Hb + k4 * 4;
#pragma unroll
    for (int m = 0; m < 8; ++m) {
      const float4 av = *(const float4*)(hpa + m * 16 * HH);
      const float4 bv = *(const float4*)(hpb + m * 16 * HH);
      const v2f a1 = {av.x, av.y}, a2 = {av.z, av.w};
      const v2f b1v = {bv.x, bv.y}, b2v = {bv.z, bv.w};
      acc[m] = __builtin_elementwise_fma(a1, wa1, acc[m]);
      acc[m] = __builtin_elementwise_fma(a2, wb1, acc[m]);
      acc[m] = __builtin_elementwise_fma(b1v, wa2, acc[m]);
      acc[m] = __builtin_elementwise_fma(b2v, wb2, acc[m]);
    }
  }
  const float bb = s_b[g16];
#pragma unroll
  for (int m = 0; m < 8; ++m) {
    const int rr = rr0 + 16 * m;
    const float val = acc[m].x + acc[m].y + bb;
    const float fv = __shfl_xor(val, 4);
    const float gv = __shfl_xor(val, 8);
    const float ov = __shfl_xor(val, 12);
    if (g16 < 4) {
      const int jc = CG * 4 + g16;
      float c = g_C1[rr][jc];
      g_H1[nxt][rr][jc] = cellupd(val, fv, gv, ov, c);
      g_C1[rr][jc] = c;
    }
  }
}

__global__ __launch_bounds__(256, 4) void dec_pred(
    const float* __restrict__ w_out, const float* __restrict__ b_out,
    float* __restrict__ out, int d) {
  const int tid = threadIdx.x;
  const int nxt = (d & 1) ^ 1;
  const int r = blockIdx.x * 4 + (tid >> 6);
  const int lane = tid & 63;
  const float4* hp = (const float4*)&g_H1[nxt][r][0];
  const float4* wp = (const float4*)w_out;
  const float4 a0 = hp[lane * 2], a1 = hp[lane * 2 + 1];
  const float4 w0 = wp[lane * 2], w1 = wp[lane * 2 + 1];
  float pv = a0.x * w0.x + a0.y * w0.y + a0.z * w0.z + a0.w * w0.w +
             a1.x * w1.x + a1.y * w1.y + a1.z * w1.z + a1.w * w1.w;
#pragma unroll
  for (int off = 32; off; off >>= 1) pv += __shfl_down(pv, off);
  if (lane == 0) {
    const float tot = pv + b_out[0];
    g_u[r] = tot;
    out[r * HOR + d] = tot;
  }
}

extern "C" void kernel_launch(void* const* d_in, const int* in_sizes, int n_in,
                              void* d_out, int out_size, void* d_ws, size_t ws_size,
                              hipStream_t stream) {
  (void)in_sizes; (void)n_in; (void)out_size; (void)ws_size;
  const float* x = (const float*)d_in[0];
  const float* init_input = (const float*)d_in[1];
  const float* w_ih0 = (const float*)d_in[2];
  const float* w_hh0 = (const float*)d_in[3];
  const float* b0 = (const float*)d_in[4];
  const float* w_ih1 = (const float*)d_in[5];
  const float* w_hh1 = (const float*)d_in[6];
  const float* b1 = (const float*)d_in[7];
  const float* w_out = (const float*)d_in[8];
  const float* b_out = (const float*)d_in[9];
  float* out = (float*)d_out;

  hipMemsetAsync(d_ws, 0, 256, stream);
  enc_kernel<<<NWG, NT, 0, stream>>>(x, init_input, w_ih0, w_hh0, b0,
                                     w_ih1, w_hh1, b1, (unsigned*)d_ws);
  for (int d = 0; d < HOR; ++d) {
    dec_l0<<<1024, 256, 0, stream>>>(w_hh0, w_ih0, b0, d);
    dec_l1<<<1024, 256, 0, stream>>>(w_ih1, w_hh1, b1, d);
    dec_pred<<<256, 256, 0, stream>>>(w_out, b_out, out, d);
  }
}

// Round 6
// 30275.806 us; speedup vs baseline: 2.3385x; 1.3222x over previous
//
#include <hip/hip_runtime.h>
#include <math.h>

// Problem constants (fixed by setup_inputs)
#define NWG 256
#define NT  512
#define BB  64      // batch
#define TT  512     // seq len
#define HH  512     // hidden
#define RR  1024    // decode rows = B*S
#define HOR 64      // horizon
#define WST 520     // encoder LDS weight row stride (floats)

// decoder GEMM tile
#define DM 64       // rows per WG tile
#define DN 128      // gate-cols per WG tile (= 32 hcols x 4 gates interleaved)
#define DK 64       // k tile
#define APAD 65
#define BPAD 133

typedef float v2f __attribute__((ext_vector_type(2)));

// Persistent state in device globals (re-initialized every launch)
__device__ float g_h0[2][BB][HH];
__device__ float g_h1[2][BB][HH];
__device__ float g_c0[BB][HH];
__device__ float g_c1[BB][HH];
__device__ float g_H0[2][RR][HH];
__device__ float g_H1[2][RR][HH];
__device__ float g_C0[RR][HH];
__device__ float g_C1[RR][HH];
__device__ float g_u[RR];

__device__ __forceinline__ float sigf(float v) { return 1.0f / (1.0f + expf(-v)); }

__device__ __forceinline__ float cellupd(float iv, float fv, float gv, float ov, float& c) {
  c = sigf(fv) * c + sigf(iv) * tanhf(gv);
  return sigf(ov) * tanhf(c);
}

// Two-level grid barrier (encoder only). ws layout (unsigned idx):
//   grp counter g at idx g*32 (128B apart), master at idx 320, flag at idx 384.
// 32 RMWs per group line (8 lines in parallel) + 8 master RMWs; spinners poll
// the read-shared flag line only. SAFETY RULE (R2/R4 hangs): encoder resources
// (54KB LDS, launch_bounds(512,4) => VGPR<=128) must keep >=2 WG/CU slack.
__device__ __forceinline__ void gridbar(unsigned* ws, unsigned& p, int wg) {
  __syncthreads();
  ++p;
  if (threadIdx.x == 0) {
    unsigned old = __hip_atomic_fetch_add(ws + (wg & 7) * 32, 1u,
                                          __ATOMIC_ACQ_REL, __HIP_MEMORY_SCOPE_AGENT);
    if (old + 1 == 32u * p) {
      unsigned om = __hip_atomic_fetch_add(ws + 320, 1u,
                                           __ATOMIC_ACQ_REL, __HIP_MEMORY_SCOPE_AGENT);
      if (om + 1 == 8u * p)
        __hip_atomic_store(ws + 384, p, __ATOMIC_RELEASE, __HIP_MEMORY_SCOPE_AGENT);
    }
    while (__hip_atomic_load(ws + 384, __ATOMIC_ACQUIRE, __HIP_MEMORY_SCOPE_AGENT) < p)
      __builtin_amdgcn_s_sleep(8);
  }
  __syncthreads();
}

// Reduce 16 values across a 16-lane group; lane ksl ends with reduced value
// of index ksl. (HW-verified: R5 absmax=0.)
__device__ __forceinline__ float bfly16(float (&v)[16], const int ksl) {
  float a8[8];
#pragma unroll
  for (int j = 0; j < 8; ++j) {
    const float lo = v[j], hi = v[j + 8];
    const float send = (ksl & 8) ? lo : hi;
    const float recv = __shfl_xor(send, 8);
    a8[j] = ((ksl & 8) ? hi : lo) + recv;
  }
  float a4[4];
#pragma unroll
  for (int j = 0; j < 4; ++j) {
    const float lo = a8[j], hi = a8[j + 4];
    const float send = (ksl & 4) ? lo : hi;
    const float recv = __shfl_xor(send, 4);
    a4[j] = ((ksl & 4) ? hi : lo) + recv;
  }
  float a2[2];
#pragma unroll
  for (int j = 0; j < 2; ++j) {
    const float lo = a4[j], hi = a4[j + 2];
    const float send = (ksl & 2) ? lo : hi;
    const float recv = __shfl_xor(send, 2);
    a2[j] = ((ksl & 2) ? hi : lo) + recv;
  }
  const float lo = a2[0], hi = a2[1];
  const float send = (ksl & 1) ? lo : hi;
  const float recv = __shfl_xor(send, 1);
  return ((ksl & 1) ? hi : lo) + recv;
}

// ======================= ENCODER (persistent) =======================
// Same math as R5 (absmax=0); only the barrier changed.
__global__ __launch_bounds__(NT, 4) void enc_kernel(
    const float* __restrict__ x, const float* __restrict__ init_input,
    const float* __restrict__ w_ih0, const float* __restrict__ w_hh0,
    const float* __restrict__ b0, const float* __restrict__ w_ih1,
    const float* __restrict__ w_hh1, const float* __restrict__ b1,
    unsigned* ws) {
  const int wg = blockIdx.x;
  const int tid = threadIdx.x;
  const int jh0 = wg * 2;

  __shared__ __align__(16) float s_whh0[8 * WST];
  __shared__ __align__(16) float s_wih1[8 * WST];
  __shared__ __align__(16) float s_whh1[8 * WST];
  __shared__ __align__(16) float s_gb0[64 * 8];  // [b][q][gate]
  __shared__ __align__(16) float s_gb1[64 * 8];
  __shared__ float s_wih0[8], s_b0[8], s_b1[8];

  for (int r8 = 0; r8 < 8; ++r8) {
    int gate = r8 >> 1, q = r8 & 1;
    int j = gate * HH + jh0 + q;
    s_whh0[r8 * WST + tid] = w_hh0[j * HH + tid];
    s_wih1[r8 * WST + tid] = w_ih1[j * HH + tid];
    s_whh1[r8 * WST + tid] = w_hh1[j * HH + tid];
  }
  if (tid < 8) {
    int gate = tid >> 1, q = tid & 1;
    int j = gate * HH + jh0 + q;
    s_wih0[tid] = w_ih0[j];
    s_b0[tid] = b0[j];
    s_b1[tid] = b1[j];
  }
  {  // zero-init encoder state
    int idx = wg * NT + tid;
    if (idx < 2 * BB * HH) {
      (&g_h0[0][0][0])[idx] = 0.f;
      (&g_h1[0][0][0])[idx] = 0.f;
    }
    if (idx < BB * HH) {
      (&g_c0[0][0])[idx] = 0.f;
      (&g_c1[0][0])[idx] = 0.f;
    }
  }
  unsigned phase = 0;
  gridbar(ws, phase, wg);

  const int grp = tid >> 4;          // 32 row-groups -> rows grp*2, grp*2+1
  const int ksl = tid & 15;          // K-split 16: k = ksl*4 + j*64
  const int b0r = grp * 2;
  const int eb = b0r + (ksl >> 3);   // butterfly output: batch row
  const int r8o = ksl & 7;           // butterfly output: gate-row (gate*2+q)
  const int eslot = eb * 8 + ((r8o & 1) << 2) + (r8o >> 1);

  for (int tk = 1; tk <= TT + 1; ++tk) {
    const int cur = (tk - 1) & 1, nxt = tk & 1;

    if (tk <= TT) {  // ---- L0 matmul: gates0 = h0[cur] @ whh0^T ----
      float acc[16];
#pragma unroll
      for (int v = 0; v < 16; ++v) acc[v] = 0.f;
#pragma unroll
      for (int j = 0; j < 8; ++j) {
        const int k = ksl * 4 + j * 64;
        float4 hv[2];
#pragma unroll
        for (int r = 0; r < 2; ++r) hv[r] = *(const float4*)&g_h0[cur][b0r + r][k];
#pragma unroll
        for (int g = 0; g < 8; ++g) {
          const float4 wv = *(const float4*)&s_whh0[g * WST + k];
#pragma unroll
          for (int r = 0; r < 2; ++r) {
            acc[r * 8 + g] = fmaf(hv[r].x, wv.x, acc[r * 8 + g]);
            acc[r * 8 + g] = fmaf(hv[r].y, wv.y, acc[r * 8 + g]);
            acc[r * 8 + g] = fmaf(hv[r].z, wv.z, acc[r * 8 + g]);
            acc[r * 8 + g] = fmaf(hv[r].w, wv.w, acc[r * 8 + g]);
          }
        }
      }
      float v0 = bfly16(acc, ksl);
      v0 += x[eb * TT + (tk - 1)] * s_wih0[r8o] + s_b0[r8o];
      s_gb0[eslot] = v0;
    }

    if (tk >= 2) {  // ---- L1: gates1 = h0[cur] @ wih1^T + h1^{tk-2} @ whh1^T ----
      float acc[16];
#pragma unroll
      for (int v = 0; v < 16; ++v) acc[v] = 0.f;
#pragma unroll
      for (int j = 0; j < 8; ++j) {
        const int k = ksl * 4 + j * 64;
        float4 hv[2];
#pragma unroll
        for (int r = 0; r < 2; ++r) hv[r] = *(const float4*)&g_h0[cur][b0r + r][k];
#pragma unroll
        for (int g = 0; g < 8; ++g) {
          const float4 wv = *(const float4*)&s_wih1[g * WST + k];
#pragma unroll
          for (int r = 0; r < 2; ++r) {
            acc[r * 8 + g] = fmaf(hv[r].x, wv.x, acc[r * 8 + g]);
            acc[r * 8 + g] = fmaf(hv[r].y, wv.y, acc[r * 8 + g]);
            acc[r * 8 + g] = fmaf(hv[r].z, wv.z, acc[r * 8 + g]);
            acc[r * 8 + g] = fmaf(hv[r].w, wv.w, acc[r * 8 + g]);
          }
        }
#pragma unroll
        for (int r = 0; r < 2; ++r) hv[r] = *(const float4*)&g_h1[nxt][b0r + r][k];
#pragma unroll
        for (int g = 0; g < 8; ++g) {
          const float4 wv = *(const float4*)&s_whh1[g * WST + k];
#pragma unroll
          for (int r = 0; r < 2; ++r) {
            acc[r * 8 + g] = fmaf(hv[r].x, wv.x, acc[r * 8 + g]);
            acc[r * 8 + g] = fmaf(hv[r].y, wv.y, acc[r * 8 + g]);
            acc[r * 8 + g] = fmaf(hv[r].z, wv.z, acc[r * 8 + g]);
            acc[r * 8 + g] = fmaf(hv[r].w, wv.w, acc[r * 8 + g]);
          }
        }
      }
      s_gb1[eslot] = bfly16(acc, ksl) + s_b1[r8o];
    }
    __syncthreads();

    if (tk <= TT && tid < 128) {  // cell0 -> h0^{tk}
      const int b = tid >> 1, q = tid & 1, jh = jh0 + q;
      const float4 gv = *(const float4*)&s_gb0[(b << 3) + (q << 2)];
      float c = g_c0[b][jh];
      g_h0[nxt][b][jh] = cellupd(gv.x, gv.y, gv.z, gv.w, c);
      g_c0[b][jh] = c;
    }
    if (tk >= 2 && tid >= 128 && tid < 256) {  // cell1 -> h1^{tk-1}
      const int t = tid - 128, b = t >> 1, q = t & 1, jh = jh0 + q;
      const float4 gv = *(const float4*)&s_gb1[(b << 3) + (q << 2)];
      float c = g_c1[b][jh];
      g_h1[cur][b][jh] = cellupd(gv.x, gv.y, gv.z, gv.w, c);
      g_c1[b][jh] = c;
    }
    gridbar(ws, phase, wg);
  }

  // ---- expand final states over n_samples: row r = b*16+s ----
  {
    int gt = wg * NT + tid;          // 0..131071 == RR*HH/4 float4 slots
    int r = gt >> 7, k4 = gt & 127;
    int b = r >> 4;
    ((float4*)&g_H0[0][r][0])[k4] = ((const float4*)&g_h0[0][b][0])[k4];
    ((float4*)&g_C0[r][0])[k4] = ((const float4*)&g_c0[b][0])[k4];
    ((float4*)&g_H1[0][r][0])[k4] = ((const float4*)&g_h1[0][b][0])[k4];
    ((float4*)&g_C1[r][0])[k4] = ((const float4*)&g_c1[b][0])[k4];
    if (gt < RR) g_u[gt] = init_input[gt];
  }
}

// ======================= DECODER (per-step GEMM kernels) =======================
// No grid barriers: kernel boundaries are the global sync (cannot deadlock).
// Grid 256 WGs x 256 thr: CG = bid&15 (32 hcols), RQ = bid>>4 (64 rows).
// B-tile columns are gate-interleaved: local col j -> jsrc = (j&3)*HH +
// CG*32 + (j>>2), so each thread owns ALL 4 gates of its (row, hcol) pairs
// and the LSTM cell update fuses into the epilogue (no exchange at all).

__global__ __launch_bounds__(256, 2) void dec_l0(
    const float* __restrict__ w_hh0, const float* __restrict__ w_ih0,
    const float* __restrict__ b0, int d) {
  __shared__ float As[DK][APAD];   // [k][m]
  __shared__ float Bs[DK][BPAD];   // [k][j]
  __shared__ float s_wi[DN], s_bi[DN];
  const int tid = threadIdx.x;
  const int CG = blockIdx.x & 15, RQ = blockIdx.x >> 4;
  const int row0 = RQ * DM;
  const int hcol0 = CG * 32;
  const int tx = tid & 15, ty = tid >> 4;

  if (tid < DN) {
    const int jsrc = (tid & 3) * HH + hcol0 + (tid >> 2);
    s_wi[tid] = w_ih0[jsrc];
    s_bi[tid] = b0[jsrc];
  }

  const int cur = d & 1, nxt = cur ^ 1;
  const float* __restrict__ A = &g_H0[cur][0][0];

  float acc[4][8];
#pragma unroll
  for (int r = 0; r < 4; ++r)
#pragma unroll
    for (int c = 0; c < 8; ++c) acc[r][c] = 0.f;

  for (int kt = 0; kt < 8; ++kt) {
    const int k0 = kt * DK;
    __syncthreads();
#pragma unroll
    for (int i = 0; i < 4; ++i) {  // stage A: 64 rows x 64 k (transposed)
      const int q = tid + i * 256;
      const int m = q >> 4, kk = (q & 15) * 4;
      const float4 v = *(const float4*)&A[(row0 + m) * HH + k0 + kk];
      As[kk + 0][m] = v.x; As[kk + 1][m] = v.y;
      As[kk + 2][m] = v.z; As[kk + 3][m] = v.w;
    }
#pragma unroll
    for (int i = 0; i < 8; ++i) {  // stage B: 128 j x 64 k (transposed)
      const int q = tid + i * 256;
      const int j = q >> 4, kk = (q & 15) * 4;
      const int jsrc = (j & 3) * HH + hcol0 + (j >> 2);
      const float4 v = *(const float4*)&w_hh0[jsrc * HH + k0 + kk];
      Bs[kk + 0][j] = v.x; Bs[kk + 1][j] = v.y;
      Bs[kk + 2][j] = v.z; Bs[kk + 3][j] = v.w;
    }
    __syncthreads();
#pragma unroll 8
    for (int k = 0; k < DK; ++k) {
      const float4 a = *(const float4*)&As[k][ty * 4];
      const float4 bA = *(const float4*)&Bs[k][tx * 8];
      const float4 bB = *(const float4*)&Bs[k][tx * 8 + 4];
      const float av[4] = {a.x, a.y, a.z, a.w};
      const float bv[8] = {bA.x, bA.y, bA.z, bA.w, bB.x, bB.y, bB.z, bB.w};
#pragma unroll
      for (int r = 0; r < 4; ++r)
#pragma unroll
        for (int c = 0; c < 8; ++c) acc[r][c] = fmaf(av[r], bv[c], acc[r][c]);
    }
  }

#pragma unroll
  for (int r = 0; r < 4; ++r) {  // fused cell epilogue
    const int row = row0 + ty * 4 + r;
    const float u = g_u[row];
#pragma unroll
    for (int hc = 0; hc < 2; ++hc) {
      const int jb = tx * 8 + hc * 4;
      const float iv = acc[r][hc * 4 + 0] + u * s_wi[jb + 0] + s_bi[jb + 0];
      const float fv = acc[r][hc * 4 + 1] + u * s_wi[jb + 1] + s_bi[jb + 1];
      const float gv = acc[r][hc * 4 + 2] + u * s_wi[jb + 2] + s_bi[jb + 2];
      const float ov = acc[r][hc * 4 + 3] + u * s_wi[jb + 3] + s_bi[jb + 3];
      const int hcol = hcol0 + tx * 2 + hc;
      float c = g_C0[row][hcol];
      g_H0[nxt][row][hcol] = cellupd(iv, fv, gv, ov, c);
      g_C0[row][hcol] = c;
    }
  }
}

__global__ __launch_bounds__(256, 2) void dec_l1(
    const float* __restrict__ w_ih1, const float* __restrict__ w_hh1,
    const float* __restrict__ b1, int d) {
  __shared__ float As[DK][APAD];
  __shared__ float Bs[DK][BPAD];
  __shared__ float s_bi[DN];
  const int tid = threadIdx.x;
  const int CG = blockIdx.x & 15, RQ = blockIdx.x >> 4;
  const int row0 = RQ * DM;
  const int hcol0 = CG * 32;
  const int tx = tid & 15, ty = tid >> 4;

  if (tid < DN) {
    const int jsrc = (tid & 3) * HH + hcol0 + (tid >> 2);
    s_bi[tid] = b1[jsrc];
  }

  const int cur = d & 1, nxt = cur ^ 1;

  float acc[4][8];
#pragma unroll
  for (int r = 0; r < 4; ++r)
#pragma unroll
    for (int c = 0; c < 8; ++c) acc[r][c] = 0.f;

#pragma unroll
  for (int ph = 0; ph < 2; ++ph) {
    const float* __restrict__ A = ph ? &g_H1[cur][0][0] : &g_H0[nxt][0][0];
    const float* __restrict__ W = ph ? w_hh1 : w_ih1;
    for (int kt = 0; kt < 8; ++kt) {
      const int k0 = kt * DK;
      __syncthreads();
#pragma unroll
      for (int i = 0; i < 4; ++i) {
        const int q = tid + i * 256;
        const int m = q >> 4, kk = (q & 15) * 4;
        const float4 v = *(const float4*)&A[(row0 + m) * HH + k0 + kk];
        As[kk + 0][m] = v.x; As[kk + 1][m] = v.y;
        As[kk + 2][m] = v.z; As[kk + 3][m] = v.w;
      }
#pragma unroll
      for (int i = 0; i < 8; ++i) {
        const int q = tid + i * 256;
        const int j = q >> 4, kk = (q & 15) * 4;
        const int jsrc = (j & 3) * HH + hcol0 + (j >> 2);
        const float4 v = *(const float4*)&W[jsrc * HH + k0 + kk];
        Bs[kk + 0][j] = v.x; Bs[kk + 1][j] = v.y;
        Bs[kk + 2][j] = v.z; Bs[kk + 3][j] = v.w;
      }
      __syncthreads();
#pragma unroll 8
      for (int k = 0; k < DK; ++k) {
        const float4 a = *(const float4*)&As[k][ty * 4];
        const float4 bA = *(const float4*)&Bs[k][tx * 8];
        const float4 bB = *(const float4*)&Bs[k][tx * 8 + 4];
        const float av[4] = {a.x, a.y, a.z, a.w};
        const float bv[8] = {bA.x, bA.y, bA.z, bA.w, bB.x, bB.y, bB.z, bB.w};
#pragma unroll
        for (int r = 0; r < 4; ++r)
#pragma unroll
          for (int c = 0; c < 8; ++c) acc[r][c] = fmaf(av[r], bv[c], acc[r][c]);
      }
    }
  }

#pragma unroll
  for (int r = 0; r < 4; ++r) {
    const int row = row0 + ty * 4 + r;
#pragma unroll
    for (int hc = 0; hc < 2; ++hc) {
      const int jb = tx * 8 + hc * 4;
      const float iv = acc[r][hc * 4 + 0] + s_bi[jb + 0];
      const float fv = acc[r][hc * 4 + 1] + s_bi[jb + 1];
      const float gv = acc[r][hc * 4 + 2] + s_bi[jb + 2];
      const float ov = acc[r][hc * 4 + 3] + s_bi[jb + 3];
      const int hcol = hcol0 + tx * 2 + hc;
      float c = g_C1[row][hcol];
      g_H1[nxt][row][hcol] = cellupd(iv, fv, gv, ov, c);
      g_C1[row][hcol] = c;
    }
  }
}

__global__ __launch_bounds__(256, 4) void dec_pred(
    const float* __restrict__ w_out, const float* __restrict__ b_out,
    float* __restrict__ out, int d) {
  const int tid = threadIdx.x;
  const int nxt = (d & 1) ^ 1;
  const int r = blockIdx.x * 4 + (tid >> 6);
  const int lane = tid & 63;
  const float4* hp = (const float4*)&g_H1[nxt][r][0];
  const float4* wp = (const float4*)w_out;
  const float4 a0 = hp[lane * 2], a1 = hp[lane * 2 + 1];
  const float4 w0 = wp[lane * 2], w1 = wp[lane * 2 + 1];
  float pv = a0.x * w0.x + a0.y * w0.y + a0.z * w0.z + a0.w * w0.w +
             a1.x * w1.x + a1.y * w1.y + a1.z * w1.z + a1.w * w1.w;
#pragma unroll
  for (int off = 32; off; off >>= 1) pv += __shfl_down(pv, off);
  if (lane == 0) {
    const float tot = pv + b_out[0];
    g_u[r] = tot;
    out[r * HOR + d] = tot;
  }
}

extern "C" void kernel_launch(void* const* d_in, const int* in_sizes, int n_in,
                              void* d_out, int out_size, void* d_ws, size_t ws_size,
                              hipStream_t stream) {
  (void)in_sizes; (void)n_in; (void)out_size; (void)ws_size;
  const float* x = (const float*)d_in[0];
  const float* init_input = (const float*)d_in[1];
  const float* w_ih0 = (const float*)d_in[2];
  const float* w_hh0 = (const float*)d_in[3];
  const float* b0 = (const float*)d_in[4];
  const float* w_ih1 = (const float*)d_in[5];
  const float* w_hh1 = (const float*)d_in[6];
  const float* b1 = (const float*)d_in[7];
  const float* w_out = (const float*)d_in[8];
  const float* b_out = (const float*)d_in[9];
  float* out = (float*)d_out;

  hipMemsetAsync(d_ws, 0, 4096, stream);
  enc_kernel<<<NWG, NT, 0, stream>>>(x, init_input, w_ih0, w_hh0, b0,
                                     w_ih1, w_hh1, b1, (unsigned*)d_ws);
  for (int d = 0; d < HOR; ++d) {
    dec_l0<<<256, 256, 0, stream>>>(w_hh0, w_ih0, b0, d);
    dec_l1<<<256, 256, 0, stream>>>(w_ih1, w_hh1, b1, d);
    dec_pred<<<256, 256, 0, stream>>>(w_out, b_out, out, d);
  }
}

// Round 7
// 27305.060 us; speedup vs baseline: 2.5930x; 1.1088x over previous
//
#include <hip/hip_runtime.h>
#include <math.h>

// Problem constants (fixed by setup_inputs)
#define BB  64      // batch
#define TT  512     // seq len
#define HH  512     // hidden
#define RR  1024    // decode rows = B*S
#define HOR 64      // horizon
#define WST 520     // encoder LDS weight row stride (floats)

// encoder geometry
#define ENW 128     // encoder WGs (each owns 4 hcols)
#define ENT 1024    // encoder threads/WG

// decoder GEMM tile
#define DM 64       // rows per WG tile
#define DN 64       // gate-cols per WG tile (= 16 hcols x 4 gates interleaved)
#define DK 64       // k tile
#define APAD 65
#define BPAD 69

typedef float v2f __attribute__((ext_vector_type(2)));

// Persistent state in device globals (re-initialized every launch)
__device__ float g_h0[2][BB][HH];
__device__ float g_h1[2][BB][HH];
__device__ float g_c0[BB][HH];
__device__ float g_c1[BB][HH];
__device__ float g_H0[2][RR][HH];
__device__ float g_H1[2][RR][HH];
__device__ float g_C0[RR][HH];
__device__ float g_C1[RR][HH];
__device__ float g_u[RR];

__device__ __forceinline__ float sigf(float v) { return 1.0f / (1.0f + expf(-v)); }

__device__ __forceinline__ float cellupd(float iv, float fv, float gv, float ov, float& c) {
  c = sigf(fv) * c + sigf(iv) * tanhf(gv);
  return sigf(ov) * tanhf(c);
}

// Two-level grid barrier (encoder only), 128 WGs: 8 groups x 16.
// SAFETY RULE (R2/R4 hangs): all-WG co-residency needs >=2x slack.
// Here: 100KB LDS -> 1 WG/CU, 128 WGs vs 256 CUs = 2x slack. Keep it so.
__device__ __forceinline__ void gridbar(unsigned* ws, unsigned& p, int wg) {
  __syncthreads();
  ++p;
  if (threadIdx.x == 0) {
    unsigned old = __hip_atomic_fetch_add(ws + (wg & 7) * 32, 1u,
                                          __ATOMIC_ACQ_REL, __HIP_MEMORY_SCOPE_AGENT);
    if (old + 1 == 16u * p) {
      unsigned om = __hip_atomic_fetch_add(ws + 320, 1u,
                                           __ATOMIC_ACQ_REL, __HIP_MEMORY_SCOPE_AGENT);
      if (om + 1 == 8u * p)
        __hip_atomic_store(ws + 384, p, __ATOMIC_RELEASE, __HIP_MEMORY_SCOPE_AGENT);
    }
    while (__hip_atomic_load(ws + 384, __ATOMIC_ACQUIRE, __HIP_MEMORY_SCOPE_AGENT) < p)
      __builtin_amdgcn_s_sleep(8);
  }
  __syncthreads();
}

// Reduce 32 values across the 32-lane half-wave; lane ks ends with the fully
// reduced value of index ks. (HW-verified: R3/R5 absmax=0.)
__device__ __forceinline__ float bfly32(float (&v)[32], const int ks) {
  float a16[16];
#pragma unroll
  for (int j = 0; j < 16; ++j) {
    const float lo = v[j], hi = v[j + 16];
    const float send = (ks & 16) ? lo : hi;
    const float recv = __shfl_xor(send, 16);
    a16[j] = ((ks & 16) ? hi : lo) + recv;
  }
  float a8[8];
#pragma unroll
  for (int j = 0; j < 8; ++j) {
    const float lo = a16[j], hi = a16[j + 8];
    const float send = (ks & 8) ? lo : hi;
    const float recv = __shfl_xor(send, 8);
    a8[j] = ((ks & 8) ? hi : lo) + recv;
  }
  float a4[4];
#pragma unroll
  for (int j = 0; j < 4; ++j) {
    const float lo = a8[j], hi = a8[j + 4];
    const float send = (ks & 4) ? lo : hi;
    const float recv = __shfl_xor(send, 4);
    a4[j] = ((ks & 4) ? hi : lo) + recv;
  }
  float a2[2];
#pragma unroll
  for (int j = 0; j < 2; ++j) {
    const float lo = a4[j], hi = a4[j + 2];
    const float send = (ks & 2) ? lo : hi;
    const float recv = __shfl_xor(send, 2);
    a2[j] = ((ks & 2) ? hi : lo) + recv;
  }
  const float lo = a2[0], hi = a2[1];
  const float send = (ks & 1) ? lo : hi;
  const float recv = __shfl_xor(send, 1);
  return ((ks & 1) ? hi : lo) + recv;
}

// ======================= ENCODER (persistent) =======================
// 128 WGs x 1024 thr (16 waves/CU = 4/SIMD). WG owns hcols jh0..jh0+3
// -> 16 gate-rows per matrix (r16 = gate*4+q). Thread tile: 4 batch-rows x
// 8 gate-rows (gh half), K-split 32 (k = ksl*4 + j*128). v2f pk-FMA.
__global__ __launch_bounds__(ENT, 4) void enc_kernel(
    const float* __restrict__ x, const float* __restrict__ init_input,
    const float* __restrict__ w_ih0, const float* __restrict__ w_hh0,
    const float* __restrict__ b0, const float* __restrict__ w_ih1,
    const float* __restrict__ w_hh1, const float* __restrict__ b1,
    unsigned* ws) {
  const int wg = blockIdx.x;
  const int tid = threadIdx.x;
  const int jh0 = wg * 4;

  __shared__ __align__(16) float s_whh0[16 * WST];
  __shared__ __align__(16) float s_wih1[16 * WST];
  __shared__ __align__(16) float s_whh1[16 * WST];
  __shared__ __align__(16) float s_gb0[64 * 16];  // [b][q][gate]
  __shared__ __align__(16) float s_gb1[64 * 16];
  __shared__ float s_wih0[16], s_b0[16], s_b1[16];

  for (int i = tid; i < 16 * HH; i += ENT) {
    const int r16 = i >> 9, k = i & 511;
    const int j = (r16 >> 2) * HH + jh0 + (r16 & 3);  // gate=r16>>2, q=r16&3
    s_whh0[r16 * WST + k] = w_hh0[j * HH + k];
    s_wih1[r16 * WST + k] = w_ih1[j * HH + k];
    s_whh1[r16 * WST + k] = w_hh1[j * HH + k];
  }
  if (tid < 16) {
    const int j = (tid >> 2) * HH + jh0 + (tid & 3);
    s_wih0[tid] = w_ih0[j];
    s_b0[tid] = b0[j];
    s_b1[tid] = b1[j];
  }
  {  // zero-init encoder state
    int idx = wg * ENT + tid;  // 0..131071
    if (idx < 2 * BB * HH) {
      (&g_h0[0][0][0])[idx] = 0.f;
      (&g_h1[0][0][0])[idx] = 0.f;
    }
    if (idx < BB * HH) {
      (&g_c0[0][0])[idx] = 0.f;
      (&g_c1[0][0])[idx] = 0.f;
    }
  }
  unsigned phase = 0;
  gridbar(ws, phase, wg);

  const int gh = tid >> 9;           // gate-row half: rows gh*8..gh*8+7
  const int rg = (tid >> 5) & 15;    // 16 row-groups -> rows rg*4..+3
  const int ksl = tid & 31;          // K-split 32: k = ksl*4 + j*128
  const int b0r = rg * 4;
  const int eb = b0r + (ksl >> 3);         // butterfly out: batch row
  const int r16o = gh * 8 + (ksl & 7);     // butterfly out: gate-row
  const int eslot = eb * 16 + (r16o & 3) * 4 + (r16o >> 2);  // [b][q][gate]

  for (int tk = 1; tk <= TT + 1; ++tk) {
    const int cur = (tk - 1) & 1, nxt = tk & 1;

    if (tk <= TT) {  // ---- L0: gates0 = h0[cur] @ whh0^T ----
      v2f acc[32];
#pragma unroll
      for (int v = 0; v < 32; ++v) acc[v] = (v2f){0.f, 0.f};
#pragma unroll
      for (int j = 0; j < 4; ++j) {
        const int k = ksl * 4 + j * 128;
        float4 hv[4];
#pragma unroll
        for (int r = 0; r < 4; ++r) hv[r] = *(const float4*)&g_h0[cur][b0r + r][k];
#pragma unroll
        for (int g = 0; g < 8; ++g) {
          const float4 wv = *(const float4*)&s_whh0[(gh * 8 + g) * WST + k];
          const v2f w0 = {wv.x, wv.y}, w1 = {wv.z, wv.w};
#pragma unroll
          for (int r = 0; r < 4; ++r) {
            const v2f hA = {hv[r].x, hv[r].y}, hB = {hv[r].z, hv[r].w};
            acc[r * 8 + g] = __builtin_elementwise_fma(hA, w0, acc[r * 8 + g]);
            acc[r * 8 + g] = __builtin_elementwise_fma(hB, w1, acc[r * 8 + g]);
          }
        }
      }
      float s[32];
#pragma unroll
      for (int v = 0; v < 32; ++v) s[v] = acc[v].x + acc[v].y;
      float v0 = bfly32(s, ksl);
      v0 += x[eb * TT + (tk - 1)] * s_wih0[r16o] + s_b0[r16o];
      s_gb0[eslot] = v0;
    }

    if (tk >= 2) {  // ---- L1: gates1 = h0[cur] @ wih1^T + h1^{tk-2} @ whh1^T ----
      v2f acc[32];
#pragma unroll
      for (int v = 0; v < 32; ++v) acc[v] = (v2f){0.f, 0.f};
#pragma unroll
      for (int j = 0; j < 4; ++j) {
        const int k = ksl * 4 + j * 128;
        float4 hv[4];
#pragma unroll
        for (int r = 0; r < 4; ++r) hv[r] = *(const float4*)&g_h0[cur][b0r + r][k];
#pragma unroll
        for (int g = 0; g < 8; ++g) {
          const float4 wv = *(const float4*)&s_wih1[(gh * 8 + g) * WST + k];
          const v2f w0 = {wv.x, wv.y}, w1 = {wv.z, wv.w};
#pragma unroll
          for (int r = 0; r < 4; ++r) {
            const v2f hA = {hv[r].x, hv[r].y}, hB = {hv[r].z, hv[r].w};
            acc[r * 8 + g] = __builtin_elementwise_fma(hA, w0, acc[r * 8 + g]);
            acc[r * 8 + g] = __builtin_elementwise_fma(hB, w1, acc[r * 8 + g]);
          }
        }
#pragma unroll
        for (int r = 0; r < 4; ++r) hv[r] = *(const float4*)&g_h1[nxt][b0r + r][k];
#pragma unroll
        for (int g = 0; g < 8; ++g) {
          const float4 wv = *(const float4*)&s_whh1[(gh * 8 + g) * WST + k];
          const v2f w0 = {wv.x, wv.y}, w1 = {wv.z, wv.w};
#pragma unroll
          for (int r = 0; r < 4; ++r) {
            const v2f hA = {hv[r].x, hv[r].y}, hB = {hv[r].z, hv[r].w};
            acc[r * 8 + g] = __builtin_elementwise_fma(hA, w0, acc[r * 8 + g]);
            acc[r * 8 + g] = __builtin_elementwise_fma(hB, w1, acc[r * 8 + g]);
          }
        }
      }
      float s[32];
#pragma unroll
      for (int v = 0; v < 32; ++v) s[v] = acc[v].x + acc[v].y;
      s_gb1[eslot] = bfly32(s, ksl) + s_b1[r16o];
    }
    __syncthreads();

    if (tk <= TT && tid < 256) {  // cell0 -> h0^{tk}: 64 b x 4 q
      const int b = tid >> 2, q = tid & 3, jh = jh0 + q;
      const float4 gv = *(const float4*)&s_gb0[b * 16 + q * 4];
      float c = g_c0[b][jh];
      g_h0[nxt][b][jh] = cellupd(gv.x, gv.y, gv.z, gv.w, c);
      g_c0[b][jh] = c;
    }
    if (tk >= 2 && tid >= 256 && tid < 512) {  // cell1 -> h1^{tk-1}
      const int t = tid - 256, b = t >> 2, q = t & 3, jh = jh0 + q;
      const float4 gv = *(const float4*)&s_gb1[b * 16 + q * 4];
      float c = g_c1[b][jh];
      g_h1[cur][b][jh] = cellupd(gv.x, gv.y, gv.z, gv.w, c);
      g_c1[b][jh] = c;
    }
    gridbar(ws, phase, wg);
  }

  // ---- expand final states over n_samples: row r = b*16+s ----
  {
    int gt = wg * ENT + tid;         // 0..131071 == RR*HH/4 float4 slots
    int r = gt >> 7, k4 = gt & 127;
    int b = r >> 4;
    ((float4*)&g_H0[0][r][0])[k4] = ((const float4*)&g_h0[0][b][0])[k4];
    ((float4*)&g_C0[r][0])[k4] = ((const float4*)&g_c0[b][0])[k4];
    ((float4*)&g_H1[0][r][0])[k4] = ((const float4*)&g_h1[0][b][0])[k4];
    ((float4*)&g_C1[r][0])[k4] = ((const float4*)&g_c1[b][0])[k4];
    if (gt < RR) g_u[gt] = init_input[gt];
  }
}

// ======================= DECODER (per-step GEMM kernels) =======================
// Kernel boundaries = global sync (cannot deadlock). Grid 512 WGs x 256 thr
// (2 WG/CU). CG = bid&31 -> 16 hcols; RQ = bid>>5 -> 64 rows. B-tile cols
// gate-interleaved (j -> jsrc = (j&3)*HH + hcol0 + (j>>2)) so each thread
// owns all 4 gates of its (row,hcol) pairs -> cell update fused in epilogue.

__global__ __launch_bounds__(256, 2) void dec_l0(
    const float* __restrict__ w_hh0, const float* __restrict__ w_ih0,
    const float* __restrict__ b0, int d) {
  __shared__ float As[DK][APAD];   // [k][m]
  __shared__ float Bs[DK][BPAD];   // [k][j]
  __shared__ float s_wi[DN], s_bi[DN];
  const int tid = threadIdx.x;
  const int CG = blockIdx.x & 31, RQ = blockIdx.x >> 5;
  const int row0 = RQ * DM;
  const int hcol0 = CG * 16;
  const int tx = tid & 7, ty = tid >> 3;  // 8 cols x 32 row-pairs

  if (tid < DN) {
    const int jsrc = (tid & 3) * HH + hcol0 + (tid >> 2);
    s_wi[tid] = w_ih0[jsrc];
    s_bi[tid] = b0[jsrc];
  }

  const int cur = d & 1, nxt = cur ^ 1;
  const float* __restrict__ A = &g_H0[cur][0][0];

  v2f acc[2][4];
#pragma unroll
  for (int r = 0; r < 2; ++r)
#pragma unroll
    for (int c = 0; c < 4; ++c) acc[r][c] = (v2f){0.f, 0.f};

  for (int kt = 0; kt < 8; ++kt) {
    const int k0 = kt * DK;
    __syncthreads();
#pragma unroll
    for (int i = 0; i < 4; ++i) {  // stage A: 64 rows x 64 k (transposed)
      const int q = tid + i * 256;
      const int m = q >> 4, kk = (q & 15) * 4;
      const float4 v = *(const float4*)&A[(row0 + m) * HH + k0 + kk];
      As[kk + 0][m] = v.x; As[kk + 1][m] = v.y;
      As[kk + 2][m] = v.z; As[kk + 3][m] = v.w;
    }
#pragma unroll
    for (int i = 0; i < 4; ++i) {  // stage B: 64 j x 64 k (transposed)
      const int q = tid + i * 256;
      const int j = q >> 4, kk = (q & 15) * 4;
      const int jsrc = (j & 3) * HH + hcol0 + (j >> 2);
      const float4 v = *(const float4*)&w_hh0[jsrc * HH + k0 + kk];
      Bs[kk + 0][j] = v.x; Bs[kk + 1][j] = v.y;
      Bs[kk + 2][j] = v.z; Bs[kk + 3][j] = v.w;
    }
    __syncthreads();
#pragma unroll 8
    for (int k = 0; k < DK; ++k) {
      const float2 a = *(const float2*)&As[k][ty * 2];
      const float4 bA = *(const float4*)&Bs[k][tx * 8];
      const float4 bB = *(const float4*)&Bs[k][tx * 8 + 4];
      const v2f bp[4] = {{bA.x, bA.y}, {bA.z, bA.w}, {bB.x, bB.y}, {bB.z, bB.w}};
      const v2f a0 = {a.x, a.x}, a1 = {a.y, a.y};
#pragma unroll
      for (int c = 0; c < 4; ++c) {
        acc[0][c] = __builtin_elementwise_fma(a0, bp[c], acc[0][c]);
        acc[1][c] = __builtin_elementwise_fma(a1, bp[c], acc[1][c]);
      }
    }
  }

#pragma unroll
  for (int r = 0; r < 2; ++r) {  // fused cell epilogue
    const int row = row0 + ty * 2 + r;
    const float u = g_u[row];
#pragma unroll
    for (int hc = 0; hc < 2; ++hc) {
      const int jb = tx * 8 + hc * 4;
      const float iv = acc[r][hc * 2 + 0].x + u * s_wi[jb + 0] + s_bi[jb + 0];
      const float fv = acc[r][hc * 2 + 0].y + u * s_wi[jb + 1] + s_bi[jb + 1];
      const float gv = acc[r][hc * 2 + 1].x + u * s_wi[jb + 2] + s_bi[jb + 2];
      const float ov = acc[r][hc * 2 + 1].y + u * s_wi[jb + 3] + s_bi[jb + 3];
      const int hcol = hcol0 + tx * 2 + hc;
      float c = g_C0[row][hcol];
      g_H0[nxt][row][hcol] = cellupd(iv, fv, gv, ov, c);
      g_C0[row][hcol] = c;
    }
  }
}

__global__ __launch_bounds__(256, 2) void dec_l1(
    const float* __restrict__ w_ih1, const float* __restrict__ w_hh1,
    const float* __restrict__ b1, int d) {
  __shared__ float As[DK][APAD];
  __shared__ float Bs[DK][BPAD];
  __shared__ float s_bi[DN];
  const int tid = threadIdx.x;
  const int CG = blockIdx.x & 31, RQ = blockIdx.x >> 5;
  const int row0 = RQ * DM;
  const int hcol0 = CG * 16;
  const int tx = tid & 7, ty = tid >> 3;

  if (tid < DN) {
    const int jsrc = (tid & 3) * HH + hcol0 + (tid >> 2);
    s_bi[tid] = b1[jsrc];
  }

  const int cur = d & 1, nxt = cur ^ 1;

  v2f acc[2][4];
#pragma unroll
  for (int r = 0; r < 2; ++r)
#pragma unroll
    for (int c = 0; c < 4; ++c) acc[r][c] = (v2f){0.f, 0.f};

#pragma unroll
  for (int ph = 0; ph < 2; ++ph) {
    const float* __restrict__ A = ph ? &g_H1[cur][0][0] : &g_H0[nxt][0][0];
    const float* __restrict__ W = ph ? w_hh1 : w_ih1;
    for (int kt = 0; kt < 8; ++kt) {
      const int k0 = kt * DK;
      __syncthreads();
#pragma unroll
      for (int i = 0; i < 4; ++i) {
        const int q = tid + i * 256;
        const int m = q >> 4, kk = (q & 15) * 4;
        const float4 v = *(const float4*)&A[(row0 + m) * HH + k0 + kk];
        As[kk + 0][m] = v.x; As[kk + 1][m] = v.y;
        As[kk + 2][m] = v.z; As[kk + 3][m] = v.w;
      }
#pragma unroll
      for (int i = 0; i < 4; ++i) {
        const int q = tid + i * 256;
        const int j = q >> 4, kk = (q & 15) * 4;
        const int jsrc = (j & 3) * HH + hcol0 + (j >> 2);
        const float4 v = *(const float4*)&W[jsrc * HH + k0 + kk];
        Bs[kk + 0][j] = v.x; Bs[kk + 1][j] = v.y;
        Bs[kk + 2][j] = v.z; Bs[kk + 3][j] = v.w;
      }
      __syncthreads();
#pragma unroll 8
      for (int k = 0; k < DK; ++k) {
        const float2 a = *(const float2*)&As[k][ty * 2];
        const float4 bA = *(const float4*)&Bs[k][tx * 8];
        const float4 bB = *(const float4*)&Bs[k][tx * 8 + 4];
        const v2f bp[4] = {{bA.x, bA.y}, {bA.z, bA.w}, {bB.x, bB.y}, {bB.z, bB.w}};
        const v2f a0 = {a.x, a.x}, a1 = {a.y, a.y};
#pragma unroll
        for (int c = 0; c < 4; ++c) {
          acc[0][c] = __builtin_elementwise_fma(a0, bp[c], acc[0][c]);
          acc[1][c] = __builtin_elementwise_fma(a1, bp[c], acc[1][c]);
        }
      }
    }
  }

#pragma unroll
  for (int r = 0; r < 2; ++r) {
    const int row = row0 + ty * 2 + r;
#pragma unroll
    for (int hc = 0; hc < 2; ++hc) {
      const int jb = tx * 8 + hc * 4;
      const float iv = acc[r][hc * 2 + 0].x + s_bi[jb + 0];
      const float fv = acc[r][hc * 2 + 0].y + s_bi[jb + 1];
      const float gv = acc[r][hc * 2 + 1].x + s_bi[jb + 2];
      const float ov = acc[r][hc * 2 + 1].y + s_bi[jb + 3];
      const int hcol = hcol0 + tx * 2 + hc;
      float c = g_C1[row][hcol];
      g_H1[nxt][row][hcol] = cellupd(iv, fv, gv, ov, c);
      g_C1[row][hcol] = c;
    }
  }
}

__global__ __launch_bounds__(256, 4) void dec_pred(
    const float* __restrict__ w_out, const float* __restrict__ b_out,
    float* __restrict__ out, int d) {
  const int tid = threadIdx.x;
  const int nxt = (d & 1) ^ 1;
  const int r = blockIdx.x * 4 + (tid >> 6);
  const int lane = tid & 63;
  const float4* hp = (const float4*)&g_H1[nxt][r][0];
  const float4* wp = (const float4*)w_out;
  const float4 a0 = hp[lane * 2], a1 = hp[lane * 2 + 1];
  const float4 w0 = wp[lane * 2], w1 = wp[lane * 2 + 1];
  float pv = a0.x * w0.x + a0.y * w0.y + a0.z * w0.z + a0.w * w0.w +
             a1.x * w1.x + a1.y * w1.y + a1.z * w1.z + a1.w * w1.w;
#pragma unroll
  for (int off = 32; off; off >>= 1) pv += __shfl_down(pv, off);
  if (lane == 0) {
    const float tot = pv + b_out[0];
    g_u[r] = tot;
    out[r * HOR + d] = tot;
  }
}

extern "C" void kernel_launch(void* const* d_in, const int* in_sizes, int n_in,
                              void* d_out, int out_size, void* d_ws, size_t ws_size,
                              hipStream_t stream) {
  (void)in_sizes; (void)n_in; (void)out_size; (void)ws_size;
  const float* x = (const float*)d_in[0];
  const float* init_input = (const float*)d_in[1];
  const float* w_ih0 = (const float*)d_in[2];
  const float* w_hh0 = (const float*)d_in[3];
  const float* b0 = (const float*)d_in[4];
  const float* w_ih1 = (const float*)d_in[5];
  const float* w_hh1 = (const float*)d_in[6];
  const float* b1 = (const float*)d_in[7];
  const float* w_out = (const float*)d_in[8];
  const float* b_out = (const float*)d_in[9];
  float* out = (float*)d_out;

  hipMemsetAsync(d_ws, 0, 4096, stream);
  enc_kernel<<<ENW, ENT, 0, stream>>>(x, init_input, w_ih0, w_hh0, b0,
                                      w_ih1, w_hh1, b1, (unsigned*)d_ws);
  for (int d = 0; d < HOR; ++d) {
    dec_l0<<<512, 256, 0, stream>>>(w_hh0, w_ih0, b0, d);
    dec_l1<<<512, 256, 0, stream>>>(w_ih1, w_hh1, b1, d);
    dec_pred<<<256, 256, 0, stream>>>(w_out, b_out, out, d);
  }
}

// Round 8
// 25177.502 us; speedup vs baseline: 2.8121x; 1.0845x over previous
//
#include <hip/hip_runtime.h>
#include <math.h>

// Problem constants (fixed by setup_inputs)
#define BB  64      // batch
#define TT  512     // seq len
#define HH  512     // hidden
#define RR  1024    // decode rows = B*S
#define HOR 64      // horizon
#define WST 520     // encoder LDS weight row stride (floats)

// encoder geometry
#define ENW 128     // encoder WGs (each owns 4 hcols)
#define ENT 1024    // encoder threads/WG

// decoder GEMM tile
#define DM 64       // rows per WG tile
#define DN 64       // gate-cols per WG tile (= 16 hcols x 4 gates interleaved)
#define DK 64       // k tile
#define APAD 66
#define BPAD 68

// Persistent state in device globals (re-initialized every launch)
__device__ float g_h0[2][BB][HH];
__device__ float g_h1[2][BB][HH];
__device__ float g_c0[BB][HH];
__device__ float g_c1[BB][HH];
__device__ float g_H0[2][RR][HH];
__device__ float g_H1[2][RR][HH];
__device__ float g_C0[RR][HH];
__device__ float g_C1[RR][HH];
__device__ float g_u[2][RR];   // u double-buffer: g_u[d&1] is input to step d

__device__ __forceinline__ float sigf(float v) { return 1.0f / (1.0f + expf(-v)); }

__device__ __forceinline__ float cellupd(float iv, float fv, float gv, float ov, float& c) {
  c = sigf(fv) * c + sigf(iv) * tanhf(gv);
  return sigf(ov) * tanhf(c);
}

// Two-level grid barrier (encoder only), 128 WGs: 8 groups x 16.
// SAFETY RULE (R2/R4 hangs): all-WG co-residency needs >=2x slack.
// 108KB LDS -> 1 WG/CU, 128 WGs vs 256 CUs = 2x slack. Keep it so.
__device__ __forceinline__ void gridbar(unsigned* ws, unsigned& p, int wg) {
  __syncthreads();
  ++p;
  if (threadIdx.x == 0) {
    unsigned old = __hip_atomic_fetch_add(ws + (wg & 7) * 32, 1u,
                                          __ATOMIC_ACQ_REL, __HIP_MEMORY_SCOPE_AGENT);
    if (old + 1 == 16u * p) {
      unsigned om = __hip_atomic_fetch_add(ws + 320, 1u,
                                           __ATOMIC_ACQ_REL, __HIP_MEMORY_SCOPE_AGENT);
      if (om + 1 == 8u * p)
        __hip_atomic_store(ws + 384, p, __ATOMIC_RELEASE, __HIP_MEMORY_SCOPE_AGENT);
    }
    while (__hip_atomic_load(ws + 384, __ATOMIC_ACQUIRE, __HIP_MEMORY_SCOPE_AGENT) < p)
      __builtin_amdgcn_s_sleep(8);
  }
  __syncthreads();
}

// Reduce 16 values across a 16-lane group; lane ksl ends with reduced value
// of index ksl. (HW-verified R5/R6 absmax=0.)
__device__ __forceinline__ float bfly16(float (&v)[16], const int ksl) {
  float a8[8];
#pragma unroll
  for (int j = 0; j < 8; ++j) {
    const float lo = v[j], hi = v[j + 8];
    const float send = (ksl & 8) ? lo : hi;
    const float recv = __shfl_xor(send, 8);
    a8[j] = ((ksl & 8) ? hi : lo) + recv;
  }
  float a4[4];
#pragma unroll
  for (int j = 0; j < 4; ++j) {
    const float lo = a8[j], hi = a8[j + 4];
    const float send = (ksl & 4) ? lo : hi;
    const float recv = __shfl_xor(send, 4);
    a4[j] = ((ksl & 4) ? hi : lo) + recv;
  }
  float a2[2];
#pragma unroll
  for (int j = 0; j < 2; ++j) {
    const float lo = a4[j], hi = a4[j + 2];
    const float send = (ksl & 2) ? lo : hi;
    const float recv = __shfl_xor(send, 2);
    a2[j] = ((ksl & 2) ? hi : lo) + recv;
  }
  const float lo = a2[0], hi = a2[1];
  const float send = (ksl & 1) ? lo : hi;
  const float recv = __shfl_xor(send, 1);
  return ((ksl & 1) ? hi : lo) + recv;
}

// ======================= ENCODER (persistent) =======================
// 128 WGs x 1024 thr. WG owns hcols jh0..jh0+3 (16 gate-rows/matrix).
// Thread: gh(2) x rg(32: 2 batch-rows) x ksl(16: k = ksl*4 + j*64).
// h0 block pre-loaded into 16 float4 regs (deep in-flight), used for BOTH
// L0 (whh0) and L1's wih1 term; then h1 block reuses the same regs.
__global__ __launch_bounds__(ENT, 4) void enc_kernel(
    const float* __restrict__ x, const float* __restrict__ init_input,
    const float* __restrict__ w_ih0, const float* __restrict__ w_hh0,
    const float* __restrict__ b0, const float* __restrict__ w_ih1,
    const float* __restrict__ w_hh1, const float* __restrict__ b1,
    unsigned* ws) {
  const int wg = blockIdx.x;
  const int tid = threadIdx.x;
  const int jh0 = wg * 4;

  __shared__ __align__(16) float s_whh0[16 * WST];
  __shared__ __align__(16) float s_wih1[16 * WST];
  __shared__ __align__(16) float s_whh1[16 * WST];
  __shared__ __align__(16) float s_gb0[64 * 16];  // [b][q][gate]
  __shared__ __align__(16) float s_gb1[64 * 16];
  __shared__ float s_wih0[16], s_b0[16], s_b1[16];

  for (int i = tid; i < 16 * HH; i += ENT) {
    const int r16 = i >> 9, k = i & 511;
    const int j = (r16 >> 2) * HH + jh0 + (r16 & 3);  // gate=r16>>2, q=r16&3
    s_whh0[r16 * WST + k] = w_hh0[j * HH + k];
    s_wih1[r16 * WST + k] = w_ih1[j * HH + k];
    s_whh1[r16 * WST + k] = w_hh1[j * HH + k];
  }
  if (tid < 16) {
    const int j = (tid >> 2) * HH + jh0 + (tid & 3);
    s_wih0[tid] = w_ih0[j];
    s_b0[tid] = b0[j];
    s_b1[tid] = b1[j];
  }
  {  // zero-init encoder state
    int idx = wg * ENT + tid;  // 0..131071
    if (idx < 2 * BB * HH) {
      (&g_h0[0][0][0])[idx] = 0.f;
      (&g_h1[0][0][0])[idx] = 0.f;
    }
    if (idx < BB * HH) {
      (&g_c0[0][0])[idx] = 0.f;
      (&g_c1[0][0])[idx] = 0.f;
    }
  }
  unsigned phase = 0;
  gridbar(ws, phase, wg);

  const int gh = tid >> 9;           // gate-row half: rows gh*8..gh*8+7
  const int rg = (tid >> 4) & 31;    // 32 row-groups -> rows rg*2, rg*2+1
  const int ksl = tid & 15;          // K-split 16: k = ksl*4 + j*64
  const int b0r = rg * 2;
  const int eb = b0r + (ksl >> 3);         // butterfly out: batch row
  const int r16o = gh * 8 + (ksl & 7);     // butterfly out: gate-row
  const int eslot = eb * 16 + (r16o & 3) * 4 + (r16o >> 2);  // [b][q][gate]

  for (int tk = 1; tk <= TT + 1; ++tk) {
    const int cur = (tk - 1) & 1, nxt = tk & 1;
    const bool do0 = (tk <= TT), do1 = (tk >= 2);

    // ---- preload h0[cur] block: 2 rows x 8 j -> 16 float4 in flight ----
    float4 hv[16];
#pragma unroll
    for (int j = 0; j < 8; ++j) {
      const int k = ksl * 4 + j * 64;
      hv[j * 2 + 0] = *(const float4*)&g_h0[cur][b0r + 0][k];
      hv[j * 2 + 1] = *(const float4*)&g_h0[cur][b0r + 1][k];
    }

    float acc1[16];
#pragma unroll
    for (int v = 0; v < 16; ++v) acc1[v] = 0.f;

    if (do1) {  // L1 wih1 term from the same h0 block
#pragma unroll
      for (int j = 0; j < 8; ++j) {
        const int k = ksl * 4 + j * 64;
#pragma unroll
        for (int g = 0; g < 8; ++g) {
          const float4 wv = *(const float4*)&s_wih1[(gh * 8 + g) * WST + k];
#pragma unroll
          for (int r = 0; r < 2; ++r) {
            acc1[r * 8 + g] = fmaf(hv[j * 2 + r].x, wv.x, acc1[r * 8 + g]);
            acc1[r * 8 + g] = fmaf(hv[j * 2 + r].y, wv.y, acc1[r * 8 + g]);
            acc1[r * 8 + g] = fmaf(hv[j * 2 + r].z, wv.z, acc1[r * 8 + g]);
            acc1[r * 8 + g] = fmaf(hv[j * 2 + r].w, wv.w, acc1[r * 8 + g]);
          }
        }
      }
    }

    if (do0) {  // L0: whh0 from the h0 block
      float acc0[16];
#pragma unroll
      for (int v = 0; v < 16; ++v) acc0[v] = 0.f;
#pragma unroll
      for (int j = 0; j < 8; ++j) {
        const int k = ksl * 4 + j * 64;
#pragma unroll
        for (int g = 0; g < 8; ++g) {
          const float4 wv = *(const float4*)&s_whh0[(gh * 8 + g) * WST + k];
#pragma unroll
          for (int r = 0; r < 2; ++r) {
            acc0[r * 8 + g] = fmaf(hv[j * 2 + r].x, wv.x, acc0[r * 8 + g]);
            acc0[r * 8 + g] = fmaf(hv[j * 2 + r].y, wv.y, acc0[r * 8 + g]);
            acc0[r * 8 + g] = fmaf(hv[j * 2 + r].z, wv.z, acc0[r * 8 + g]);
            acc0[r * 8 + g] = fmaf(hv[j * 2 + r].w, wv.w, acc0[r * 8 + g]);
          }
        }
      }
      float v0 = bfly16(acc0, ksl);
      v0 += x[eb * TT + (tk - 1)] * s_wih0[r16o] + s_b0[r16o];
      s_gb0[eslot] = v0;
    }

    if (do1) {  // L1: whh1 term from h1^{tk-2} block (reuses hv regs)
#pragma unroll
      for (int j = 0; j < 8; ++j) {
        const int k = ksl * 4 + j * 64;
        hv[j * 2 + 0] = *(const float4*)&g_h1[nxt][b0r + 0][k];
        hv[j * 2 + 1] = *(const float4*)&g_h1[nxt][b0r + 1][k];
      }
#pragma unroll
      for (int j = 0; j < 8; ++j) {
        const int k = ksl * 4 + j * 64;
#pragma unroll
        for (int g = 0; g < 8; ++g) {
          const float4 wv = *(const float4*)&s_whh1[(gh * 8 + g) * WST + k];
#pragma unroll
          for (int r = 0; r < 2; ++r) {
            acc1[r * 8 + g] = fmaf(hv[j * 2 + r].x, wv.x, acc1[r * 8 + g]);
            acc1[r * 8 + g] = fmaf(hv[j * 2 + r].y, wv.y, acc1[r * 8 + g]);
            acc1[r * 8 + g] = fmaf(hv[j * 2 + r].z, wv.z, acc1[r * 8 + g]);
            acc1[r * 8 + g] = fmaf(hv[j * 2 + r].w, wv.w, acc1[r * 8 + g]);
          }
        }
      }
      s_gb1[eslot] = bfly16(acc1, ksl) + s_b1[r16o];
    }
    __syncthreads();

    if (do0 && tid < 256) {  // cell0 -> h0^{tk}: 64 b x 4 q
      const int b = tid >> 2, q = tid & 3, jh = jh0 + q;
      const float4 gv = *(const float4*)&s_gb0[b * 16 + q * 4];
      float c = g_c0[b][jh];
      g_h0[nxt][b][jh] = cellupd(gv.x, gv.y, gv.z, gv.w, c);
      g_c0[b][jh] = c;
    }
    if (do1 && tid >= 256 && tid < 512) {  // cell1 -> h1^{tk-1}
      const int t = tid - 256, b = t >> 2, q = t & 3, jh = jh0 + q;
      const float4 gv = *(const float4*)&s_gb1[b * 16 + q * 4];
      float c = g_c1[b][jh];
      g_h1[cur][b][jh] = cellupd(gv.x, gv.y, gv.z, gv.w, c);
      g_c1[b][jh] = c;
    }
    gridbar(ws, phase, wg);
  }

  // ---- expand final states over n_samples: row r = b*16+s ----
  {
    int gt = wg * ENT + tid;         // 0..131071 == RR*HH/4 float4 slots
    int r = gt >> 7, k4 = gt & 127;
    int b = r >> 4;
    ((float4*)&g_H0[0][r][0])[k4] = ((const float4*)&g_h0[0][b][0])[k4];
    ((float4*)&g_C0[r][0])[k4] = ((const float4*)&g_c0[b][0])[k4];
    ((float4*)&g_H1[0][r][0])[k4] = ((const float4*)&g_h1[0][b][0])[k4];
    ((float4*)&g_C1[r][0])[k4] = ((const float4*)&g_c1[b][0])[k4];
    if (gt < RR) g_u[0][gt] = init_input[gt];
  }
}

// ======================= DECODER (per-step GEMM kernels) =======================
// Kernel boundaries = global sync. Grid 512 WGs x 512 thr (2 WG/CU, 16 waves).
// CG = bid&31 -> 16 hcols; RQ = bid>>5 -> 64 rows. B cols gate-interleaved
// (j -> jsrc = (j&3)*HH + hcol0 + (j>>2)); thread owns 2 rows x 1 hcol (all 4
// gates) -> cell update fused in epilogue, pred folded into l1 via atomics.

__global__ __launch_bounds__(512, 4) void dec_l0(
    const float* __restrict__ w_hh0, const float* __restrict__ w_ih0,
    const float* __restrict__ b0, const float* __restrict__ b_out,
    float* __restrict__ out, int d) {
  __shared__ float As[DK][APAD];   // [k][m]
  __shared__ float Bs[DK][BPAD];   // [k][j]
  __shared__ float s_wi[DN], s_bi[DN];
  const int tid = threadIdx.x;
  const int CG = blockIdx.x & 31, RQ = blockIdx.x >> 5;
  const int row0 = RQ * DM;
  const int hcol0 = CG * 16;
  const int tx = tid & 15, ty = tid >> 4;  // hcol, row-pair

  if (tid < DN) {
    const int jsrc = (tid & 3) * HH + hcol0 + (tid >> 2);
    s_wi[tid] = w_ih0[jsrc];
    s_bi[tid] = b0[jsrc];
  }

  const int cur = d & 1, nxt = cur ^ 1;
  const int ub = d & 1, nb = ub ^ 1;
  const float* __restrict__ A = &g_H0[cur][0][0];

  float acc[2][4];
#pragma unroll
  for (int r = 0; r < 2; ++r)
#pragma unroll
    for (int c = 0; c < 4; ++c) acc[r][c] = 0.f;

  for (int kt = 0; kt < 8; ++kt) {
    const int k0 = kt * DK;
    __syncthreads();
#pragma unroll
    for (int i = 0; i < 2; ++i) {  // stage A: 64 rows x 64 k (transposed)
      const int q = tid + i * 512;
      const int m = q >> 4, kk = (q & 15) * 4;
      const float4 v = *(const float4*)&A[(row0 + m) * HH + k0 + kk];
      As[kk + 0][m] = v.x; As[kk + 1][m] = v.y;
      As[kk + 2][m] = v.z; As[kk + 3][m] = v.w;
    }
#pragma unroll
    for (int i = 0; i < 2; ++i) {  // stage B: 64 j x 64 k (transposed)
      const int q = tid + i * 512;
      const int j = q >> 4, kk = (q & 15) * 4;
      const int jsrc = (j & 3) * HH + hcol0 + (j >> 2);
      const float4 v = *(const float4*)&w_hh0[jsrc * HH + k0 + kk];
      Bs[kk + 0][j] = v.x; Bs[kk + 1][j] = v.y;
      Bs[kk + 2][j] = v.z; Bs[kk + 3][j] = v.w;
    }
    __syncthreads();
#pragma unroll 16
    for (int k = 0; k < DK; ++k) {
      const float2 a = *(const float2*)&As[k][ty * 2];
      const float4 b = *(const float4*)&Bs[k][tx * 4];
      acc[0][0] = fmaf(a.x, b.x, acc[0][0]);
      acc[0][1] = fmaf(a.x, b.y, acc[0][1]);
      acc[0][2] = fmaf(a.x, b.z, acc[0][2]);
      acc[0][3] = fmaf(a.x, b.w, acc[0][3]);
      acc[1][0] = fmaf(a.y, b.x, acc[1][0]);
      acc[1][1] = fmaf(a.y, b.y, acc[1][1]);
      acc[1][2] = fmaf(a.y, b.z, acc[1][2]);
      acc[1][3] = fmaf(a.y, b.w, acc[1][3]);
    }
  }

  const int hcol = hcol0 + tx;
#pragma unroll
  for (int r = 0; r < 2; ++r) {  // fused cell epilogue
    const int row = row0 + ty * 2 + r;
    const float u = g_u[ub][row];
    const float iv = acc[r][0] + u * s_wi[tx * 4 + 0] + s_bi[tx * 4 + 0];
    const float fv = acc[r][1] + u * s_wi[tx * 4 + 1] + s_bi[tx * 4 + 1];
    const float gv = acc[r][2] + u * s_wi[tx * 4 + 2] + s_bi[tx * 4 + 2];
    const float ov = acc[r][3] + u * s_wi[tx * 4 + 3] + s_bi[tx * 4 + 3];
    float c = g_C0[row][hcol];
    g_H0[nxt][row][hcol] = cellupd(iv, fv, gv, ov, c);
    g_C0[row][hcol] = c;
  }
  if (CG == 0 && tx == 0) {  // init next-u and out[:,d] with b_out
    const float bo = b_out[0];
#pragma unroll
    for (int r = 0; r < 2; ++r) {
      const int row = row0 + ty * 2 + r;
      g_u[nb][row] = bo;
      out[row * HOR + d] = bo;
    }
  }
}

__global__ __launch_bounds__(512, 4) void dec_l1(
    const float* __restrict__ w_ih1, const float* __restrict__ w_hh1,
    const float* __restrict__ b1, const float* __restrict__ w_out,
    float* __restrict__ out, int d) {
  __shared__ float As[DK][APAD];
  __shared__ float Bs[DK][BPAD];
  __shared__ float s_bi[DN];
  const int tid = threadIdx.x;
  const int CG = blockIdx.x & 31, RQ = blockIdx.x >> 5;
  const int row0 = RQ * DM;
  const int hcol0 = CG * 16;
  const int tx = tid & 15, ty = tid >> 4;

  if (tid < DN) {
    const int jsrc = (tid & 3) * HH + hcol0 + (tid >> 2);
    s_bi[tid] = b1[jsrc];
  }

  const int cur = d & 1, nxt = cur ^ 1;
  const int nb = (d & 1) ^ 1;
  const int hcol = hcol0 + tx;
  const float wo = w_out[hcol];

  float acc[2][4];
#pragma unroll
  for (int r = 0; r < 2; ++r)
#pragma unroll
    for (int c = 0; c < 4; ++c) acc[r][c] = 0.f;

#pragma unroll
  for (int ph = 0; ph < 2; ++ph) {
    const float* __restrict__ A = ph ? &g_H1[cur][0][0] : &g_H0[nxt][0][0];
    const float* __restrict__ W = ph ? w_hh1 : w_ih1;
    for (int kt = 0; kt < 8; ++kt) {
      const int k0 = kt * DK;
      __syncthreads();
#pragma unroll
      for (int i = 0; i < 2; ++i) {
        const int q = tid + i * 512;
        const int m = q >> 4, kk = (q & 15) * 4;
        const float4 v = *(const float4*)&A[(row0 + m) * HH + k0 + kk];
        As[kk + 0][m] = v.x; As[kk + 1][m] = v.y;
        As[kk + 2][m] = v.z; As[kk + 3][m] = v.w;
      }
#pragma unroll
      for (int i = 0; i < 2; ++i) {
        const int q = tid + i * 512;
        const int j = q >> 4, kk = (q & 15) * 4;
        const int jsrc = (j & 3) * HH + hcol0 + (j >> 2);
        const float4 v = *(const float4*)&W[jsrc * HH + k0 + kk];
        Bs[kk + 0][j] = v.x; Bs[kk + 1][j] = v.y;
        Bs[kk + 2][j] = v.z; Bs[kk + 3][j] = v.w;
      }
      __syncthreads();
#pragma unroll 16
      for (int k = 0; k < DK; ++k) {
        const float2 a = *(const float2*)&As[k][ty * 2];
        const float4 b = *(const float4*)&Bs[k][tx * 4];
        acc[0][0] = fmaf(a.x, b.x, acc[0][0]);
        acc[0][1] = fmaf(a.x, b.y, acc[0][1]);
        acc[0][2] = fmaf(a.x, b.z, acc[0][2]);
        acc[0][3] = fmaf(a.x, b.w, acc[0][3]);
        acc[1][0] = fmaf(a.y, b.x, acc[1][0]);
        acc[1][1] = fmaf(a.y, b.y, acc[1][1]);
        acc[1][2] = fmaf(a.y, b.z, acc[1][2]);
        acc[1][3] = fmaf(a.y, b.w, acc[1][3]);
      }
    }
  }

  float pp[2];
#pragma unroll
  for (int r = 0; r < 2; ++r) {  // fused cell epilogue + pred partial
    const int row = row0 + ty * 2 + r;
    const float iv = acc[r][0] + s_bi[tx * 4 + 0];
    const float fv = acc[r][1] + s_bi[tx * 4 + 1];
    const float gv = acc[r][2] + s_bi[tx * 4 + 2];
    const float ov = acc[r][3] + s_bi[tx * 4 + 3];
    float c = g_C1[row][hcol];
    const float h = cellupd(iv, fv, gv, ov, c);
    g_H1[nxt][row][hcol] = h;
    g_C1[row][hcol] = c;
    pp[r] = h * wo;
  }
  // reduce pred partials across the 16 hcol lanes (tx = lane&15)
#pragma unroll
  for (int off = 1; off < 16; off <<= 1) {
    pp[0] += __shfl_xor(pp[0], off);
    pp[1] += __shfl_xor(pp[1], off);
  }
  if (tx == 0) {
#pragma unroll
    for (int r = 0; r < 2; ++r) {
      const int row = row0 + ty * 2 + r;
      atomicAdd(&g_u[nb][row], pp[r]);
      atomicAdd(&out[row * HOR + d], pp[r]);
    }
  }
}

extern "C" void kernel_launch(void* const* d_in, const int* in_sizes, int n_in,
                              void* d_out, int out_size, void* d_ws, size_t ws_size,
                              hipStream_t stream) {
  (void)in_sizes; (void)n_in; (void)out_size; (void)ws_size;
  const float* x = (const float*)d_in[0];
  const float* init_input = (const float*)d_in[1];
  const float* w_ih0 = (const float*)d_in[2];
  const float* w_hh0 = (const float*)d_in[3];
  const float* b0 = (const float*)d_in[4];
  const float* w_ih1 = (const float*)d_in[5];
  const float* w_hh1 = (const float*)d_in[6];
  const float* b1 = (const float*)d_in[7];
  const float* w_out = (const float*)d_in[8];
  const float* b_out = (const float*)d_in[9];
  float* out = (float*)d_out;

  hipMemsetAsync(d_ws, 0, 4096, stream);
  enc_kernel<<<ENW, ENT, 0, stream>>>(x, init_input, w_ih0, w_hh0, b0,
                                      w_ih1, w_hh1, b1, (unsigned*)d_ws);
  for (int d = 0; d < HOR; ++d) {
    dec_l0<<<512, 512, 0, stream>>>(w_hh0, w_ih0, b0, b_out, out, d);
    dec_l1<<<512, 512, 0, stream>>>(w_ih1, w_hh1, b1, w_out, out, d);
  }
}

// Round 9
// 22199.030 us; speedup vs baseline: 3.1894x; 1.1342x over previous
//
#include <hip/hip_runtime.h>
#include <math.h>

// Problem constants (fixed by setup_inputs)
#define BB  64      // batch
#define TT  512     // seq len
#define HH  512     // hidden
#define RR  1024    // decode rows = B*S
#define HOR 64      // horizon
#define WST 520     // encoder LDS weight row stride (floats)

// encoder geometry
#define ENW 128     // encoder WGs (each owns 4 hcols)
#define ENT 1024    // encoder threads/WG

// decoder GEMM tile
#define DM 64       // rows per WG tile
#define DN 64       // gate-cols per WG tile (16 hcols x 4 gates)
#define DK 64       // k tile
#define LSTR 68     // LDS tile row stride (floats): 68*4B, 16B-aligned, 68%32=4

// Persistent state in device globals (re-initialized every launch)
__device__ float g_h0[2][BB][HH];
__device__ float g_h1[2][BB][HH];
__device__ float g_c0[BB][HH];
__device__ float g_c1[BB][HH];
__device__ float g_H0[2][RR][HH];
__device__ float g_H1[2][RR][HH];
__device__ float g_C0[RR][HH];
__device__ float g_C1[RR][HH];
__device__ float g_u[2][RR];   // u double-buffer: g_u[d&1] feeds step d

__device__ __forceinline__ float sigf(float v) { return 1.0f / (1.0f + expf(-v)); }

__device__ __forceinline__ float cellupd(float iv, float fv, float gv, float ov, float& c) {
  c = sigf(fv) * c + sigf(iv) * tanhf(gv);
  return sigf(ov) * tanhf(c);
}

// ---- Tree grid barrier (encoder only) ----
// Arrival: each WG's thread0 release-stores its phase to its OWN cacheline
// (ws[wg*32]) -- no RMW contention. WG0 lanes 0..127 poll the 128 slots in
// parallel, then thread0 release-stores the flag (ws[ENW*32+32]); all other
// WGs spin on the flag only. Epoch counters are monotonic; ws zeroed per
// launch. SAFETY (R2/R4 hangs): 108KB LDS -> 1 WG/CU; 128 WGs vs 256 CUs
// = 2x co-residency slack. Keep it so.
__device__ __forceinline__ void gridbar(unsigned* ws, unsigned& p) {
  __syncthreads();
  ++p;
  const int tid = threadIdx.x;
  unsigned* flag = ws + ENW * 32 + 32;
  if (blockIdx.x == 0) {
    if (tid == 0)
      __hip_atomic_store(ws, p, __ATOMIC_RELEASE, __HIP_MEMORY_SCOPE_AGENT);
    if (tid < ENW) {
      while (__hip_atomic_load(ws + tid * 32, __ATOMIC_ACQUIRE,
                               __HIP_MEMORY_SCOPE_AGENT) < p)
        __builtin_amdgcn_s_sleep(1);
    }
    __syncthreads();
    if (tid == 0)
      __hip_atomic_store(flag, p, __ATOMIC_RELEASE, __HIP_MEMORY_SCOPE_AGENT);
  } else {
    if (tid == 0) {
      __hip_atomic_store(ws + blockIdx.x * 32, p, __ATOMIC_RELEASE,
                         __HIP_MEMORY_SCOPE_AGENT);
      while (__hip_atomic_load(flag, __ATOMIC_ACQUIRE,
                               __HIP_MEMORY_SCOPE_AGENT) < p)
        __builtin_amdgcn_s_sleep(2);
    }
    __syncthreads();
  }
}

// Reduce 16 values across a 16-lane group; lane ksl ends with reduced value
// of index ksl. (HW-verified R5-R8, absmax=0.)
__device__ __forceinline__ float bfly16(float (&v)[16], const int ksl) {
  float a8[8];
#pragma unroll
  for (int j = 0; j < 8; ++j) {
    const float lo = v[j], hi = v[j + 8];
    const float send = (ksl & 8) ? lo : hi;
    const float recv = __shfl_xor(send, 8);
    a8[j] = ((ksl & 8) ? hi : lo) + recv;
  }
  float a4[4];
#pragma unroll
  for (int j = 0; j < 4; ++j) {
    const float lo = a8[j], hi = a8[j + 4];
    const float send = (ksl & 4) ? lo : hi;
    const float recv = __shfl_xor(send, 4);
    a4[j] = ((ksl & 4) ? hi : lo) + recv;
  }
  float a2[2];
#pragma unroll
  for (int j = 0; j < 2; ++j) {
    const float lo = a4[j], hi = a4[j + 2];
    const float send = (ksl & 2) ? lo : hi;
    const float recv = __shfl_xor(send, 2);
    a2[j] = ((ksl & 2) ? hi : lo) + recv;
  }
  const float lo = a2[0], hi = a2[1];
  const float send = (ksl & 1) ? lo : hi;
  const float recv = __shfl_xor(send, 1);
  return ((ksl & 1) ? hi : lo) + recv;
}

// ======================= ENCODER (persistent) =======================
// 128 WGs x 1024 thr. WG owns hcols jh0..jh0+3 (16 gate-rows/matrix).
// Thread: gh(2) x rg(32: 2 batch-rows) x ksl(16: k = ksl*4 + j*64).
// Sequential acc[16] passes (R5-proven register budget, fits 64 VGPR).
__global__ __launch_bounds__(ENT, 2) void enc_kernel(
    const float* __restrict__ x, const float* __restrict__ init_input,
    const float* __restrict__ w_ih0, const float* __restrict__ w_hh0,
    const float* __restrict__ b0, const float* __restrict__ w_ih1,
    const float* __restrict__ w_hh1, const float* __restrict__ b1,
    unsigned* ws) {
  const int wg = blockIdx.x;
  const int tid = threadIdx.x;
  const int jh0 = wg * 4;

  __shared__ __align__(16) float s_whh0[16 * WST];
  __shared__ __align__(16) float s_wih1[16 * WST];
  __shared__ __align__(16) float s_whh1[16 * WST];
  __shared__ __align__(16) float s_gb0[64 * 16];  // [b][q][gate]
  __shared__ __align__(16) float s_gb1[64 * 16];
  __shared__ float s_wih0[16], s_b0[16], s_b1[16];

  for (int i = tid; i < 16 * HH; i += ENT) {
    const int r16 = i >> 9, k = i & 511;
    const int j = (r16 >> 2) * HH + jh0 + (r16 & 3);  // gate=r16>>2, q=r16&3
    s_whh0[r16 * WST + k] = w_hh0[j * HH + k];
    s_wih1[r16 * WST + k] = w_ih1[j * HH + k];
    s_whh1[r16 * WST + k] = w_hh1[j * HH + k];
  }
  if (tid < 16) {
    const int j = (tid >> 2) * HH + jh0 + (tid & 3);
    s_wih0[tid] = w_ih0[j];
    s_b0[tid] = b0[j];
    s_b1[tid] = b1[j];
  }
  {  // zero-init encoder state
    int idx = wg * ENT + tid;  // 0..131071
    if (idx < 2 * BB * HH) {
      (&g_h0[0][0][0])[idx] = 0.f;
      (&g_h1[0][0][0])[idx] = 0.f;
    }
    if (idx < BB * HH) {
      (&g_c0[0][0])[idx] = 0.f;
      (&g_c1[0][0])[idx] = 0.f;
    }
  }
  unsigned phase = 0;
  gridbar(ws, phase);

  const int gh = tid >> 9;           // gate-row half: rows gh*8..gh*8+7
  const int rg = (tid >> 4) & 31;    // 32 row-groups -> rows rg*2, rg*2+1
  const int ksl = tid & 15;          // K-split 16: k = ksl*4 + j*64
  const int b0r = rg * 2;
  const int eb = b0r + (ksl >> 3);         // butterfly out: batch row
  const int r16o = gh * 8 + (ksl & 7);     // butterfly out: gate-row
  const int eslot = eb * 16 + (r16o & 3) * 4 + (r16o >> 2);  // [b][q][gate]

  for (int tk = 1; tk <= TT + 1; ++tk) {
    const int cur = (tk - 1) & 1, nxt = tk & 1;
    const bool do0 = (tk <= TT), do1 = (tk >= 2);

    if (do0) {  // ---- L0: gates0 = h0[cur] @ whh0^T ----
      float acc[16];
#pragma unroll
      for (int v = 0; v < 16; ++v) acc[v] = 0.f;
#pragma unroll
      for (int j = 0; j < 8; ++j) {
        const int k = ksl * 4 + j * 64;
        const float4 ha = *(const float4*)&g_h0[cur][b0r + 0][k];
        const float4 hb = *(const float4*)&g_h0[cur][b0r + 1][k];
#pragma unroll
        for (int g = 0; g < 8; ++g) {
          const float4 wv = *(const float4*)&s_whh0[(gh * 8 + g) * WST + k];
          acc[g] = fmaf(ha.x, wv.x, acc[g]);
          acc[g] = fmaf(ha.y, wv.y, acc[g]);
          acc[g] = fmaf(ha.z, wv.z, acc[g]);
          acc[g] = fmaf(ha.w, wv.w, acc[g]);
          acc[8 + g] = fmaf(hb.x, wv.x, acc[8 + g]);
          acc[8 + g] = fmaf(hb.y, wv.y, acc[8 + g]);
          acc[8 + g] = fmaf(hb.z, wv.z, acc[8 + g]);
          acc[8 + g] = fmaf(hb.w, wv.w, acc[8 + g]);
        }
      }
      float v0 = bfly16(acc, ksl);
      v0 += x[eb * TT + (tk - 1)] * s_wih0[r16o] + s_b0[r16o];
      s_gb0[eslot] = v0;
    }

    if (do1) {  // ---- L1: gates1 = h0[cur] @ wih1^T + h1^{tk-2} @ whh1^T ----
      float acc[16];
#pragma unroll
      for (int v = 0; v < 16; ++v) acc[v] = 0.f;
#pragma unroll
      for (int j = 0; j < 8; ++j) {
        const int k = ksl * 4 + j * 64;
        const float4 ha = *(const float4*)&g_h0[cur][b0r + 0][k];
        const float4 hb = *(const float4*)&g_h0[cur][b0r + 1][k];
#pragma unroll
        for (int g = 0; g < 8; ++g) {
          const float4 wv = *(const float4*)&s_wih1[(gh * 8 + g) * WST + k];
          acc[g] = fmaf(ha.x, wv.x, acc[g]);
          acc[g] = fmaf(ha.y, wv.y, acc[g]);
          acc[g] = fmaf(ha.z, wv.z, acc[g]);
          acc[g] = fmaf(ha.w, wv.w, acc[g]);
          acc[8 + g] = fmaf(hb.x, wv.x, acc[8 + g]);
          acc[8 + g] = fmaf(hb.y, wv.y, acc[8 + g]);
          acc[8 + g] = fmaf(hb.z, wv.z, acc[8 + g]);
          acc[8 + g] = fmaf(hb.w, wv.w, acc[8 + g]);
        }
      }
#pragma unroll
      for (int j = 0; j < 8; ++j) {
        const int k = ksl * 4 + j * 64;
        const float4 ha = *(const float4*)&g_h1[nxt][b0r + 0][k];
        const float4 hb = *(const float4*)&g_h1[nxt][b0r + 1][k];
#pragma unroll
        for (int g = 0; g < 8; ++g) {
          const float4 wv = *(const float4*)&s_whh1[(gh * 8 + g) * WST + k];
          acc[g] = fmaf(ha.x, wv.x, acc[g]);
          acc[g] = fmaf(ha.y, wv.y, acc[g]);
          acc[g] = fmaf(ha.z, wv.z, acc[g]);
          acc[g] = fmaf(ha.w, wv.w, acc[g]);
          acc[8 + g] = fmaf(hb.x, wv.x, acc[8 + g]);
          acc[8 + g] = fmaf(hb.y, wv.y, acc[8 + g]);
          acc[8 + g] = fmaf(hb.z, wv.z, acc[8 + g]);
          acc[8 + g] = fmaf(hb.w, wv.w, acc[8 + g]);
        }
      }
      s_gb1[eslot] = bfly16(acc, ksl) + s_b1[r16o];
    }
    __syncthreads();

    if (do0 && tid < 256) {  // cell0 -> h0^{tk}: 64 b x 4 q
      const int b = tid >> 2, q = tid & 3, jh = jh0 + q;
      const float4 gv = *(const float4*)&s_gb0[b * 16 + q * 4];
      float c = g_c0[b][jh];
      g_h0[nxt][b][jh] = cellupd(gv.x, gv.y, gv.z, gv.w, c);
      g_c0[b][jh] = c;
    }
    if (do1 && tid >= 256 && tid < 512) {  // cell1 -> h1^{tk-1}
      const int t = tid - 256, b = t >> 2, q = t & 3, jh = jh0 + q;
      const float4 gv = *(const float4*)&s_gb1[b * 16 + q * 4];
      float c = g_c1[b][jh];
      g_h1[cur][b][jh] = cellupd(gv.x, gv.y, gv.z, gv.w, c);
      g_c1[b][jh] = c;
    }
    gridbar(ws, phase);
  }

  // ---- expand final states over n_samples: row r = b*16+s ----
  {
    int gt = wg * ENT + tid;         // 0..131071 == RR*HH/4 float4 slots
    int r = gt >> 7, k4 = gt & 127;
    int b = r >> 4;
    ((float4*)&g_H0[0][r][0])[k4] = ((const float4*)&g_h0[0][b][0])[k4];
    ((float4*)&g_C0[r][0])[k4] = ((const float4*)&g_c0[b][0])[k4];
    ((float4*)&g_H1[0][r][0])[k4] = ((const float4*)&g_h1[0][b][0])[k4];
    ((float4*)&g_C1[r][0])[k4] = ((const float4*)&g_c1[b][0])[k4];
    if (gt < RR) g_u[0][gt] = init_input[gt];
  }
}

// ======================= DECODER (per-step GEMM kernels) =======================
// Kernel boundaries = global sync. 512 WGs x 512 thr. CG=bid&31 (16 hcols),
// RQ=bid>>5 (64 rows). Tiles stored NATURAL layout [row][k] stride 68
// (writes: 16 lanes sweep k -> 2-way banks; reads: consecutive rows per
// instr -> conflict-free). j = gate*16 + hcol_local; thread tx owns hcol
// hcol0+tx with gates at rows {tx,tx+16,tx+32,tx+48}; rows {ty, ty+32}.
// Cell update fused in epilogue; pred fused into l1 via shfl+atomics.

__global__ __launch_bounds__(512, 4) void dec_l0(
    const float* __restrict__ w_hh0, const float* __restrict__ w_ih0,
    const float* __restrict__ b0, const float* __restrict__ b_out,
    float* __restrict__ out, int d) {
  __shared__ __align__(16) float As[DM][LSTR];
  __shared__ __align__(16) float Bs[DN][LSTR];
  __shared__ float s_wi[DN], s_bi[DN];
  const int tid = threadIdx.x;
  const int CG = blockIdx.x & 31, RQ = blockIdx.x >> 5;
  const int row0 = RQ * DM;
  const int hcol0 = CG * 16;
  const int tx = tid & 15, ty = tid >> 4;  // hcol, row (ty, ty+32)

  if (tid < DN) {  // j = gate*16 + hl
    const int jsrc = (tid >> 4) * HH + hcol0 + (tid & 15);
    s_wi[tid] = w_ih0[jsrc];
    s_bi[tid] = b0[jsrc];
  }

  const int cur = d & 1, nxt = cur ^ 1;
  const int ub = d & 1, nb = ub ^ 1;
  const float* __restrict__ A = &g_H0[cur][0][0];

  float acc[2][4];
#pragma unroll
  for (int r = 0; r < 2; ++r)
#pragma unroll
    for (int c = 0; c < 4; ++c) acc[r][c] = 0.f;

  for (int kt = 0; kt < 8; ++kt) {
    const int k0 = kt * DK;
    __syncthreads();
#pragma unroll
    for (int i = 0; i < 2; ++i) {  // stage A [m][k]
      const int q = tid + i * 512;
      const int m = q >> 4, kk = (q & 15) * 4;
      *(float4*)&As[m][kk] = *(const float4*)&A[(row0 + m) * HH + k0 + kk];
    }
#pragma unroll
    for (int i = 0; i < 2; ++i) {  // stage B [j][k], j = gate*16+hl
      const int q = tid + i * 512;
      const int j = q >> 4, kk = (q & 15) * 4;
      const int jsrc = (j >> 4) * HH + hcol0 + (j & 15);
      *(float4*)&Bs[j][kk] = *(const float4*)&w_hh0[jsrc * HH + k0 + kk];
    }
    __syncthreads();
#pragma unroll 4
    for (int kc = 0; kc < 16; ++kc) {
      const float4 a0 = *(const float4*)&As[ty][kc * 4];
      const float4 a1 = *(const float4*)&As[ty + 32][kc * 4];
      const float4 bv0 = *(const float4*)&Bs[tx][kc * 4];
      const float4 bv1 = *(const float4*)&Bs[tx + 16][kc * 4];
      const float4 bv2 = *(const float4*)&Bs[tx + 32][kc * 4];
      const float4 bv3 = *(const float4*)&Bs[tx + 48][kc * 4];
      acc[0][0] = fmaf(a0.x, bv0.x, fmaf(a0.y, bv0.y, fmaf(a0.z, bv0.z, fmaf(a0.w, bv0.w, acc[0][0]))));
      acc[0][1] = fmaf(a0.x, bv1.x, fmaf(a0.y, bv1.y, fmaf(a0.z, bv1.z, fmaf(a0.w, bv1.w, acc[0][1]))));
      acc[0][2] = fmaf(a0.x, bv2.x, fmaf(a0.y, bv2.y, fmaf(a0.z, bv2.z, fmaf(a0.w, bv2.w, acc[0][2]))));
      acc[0][3] = fmaf(a0.x, bv3.x, fmaf(a0.y, bv3.y, fmaf(a0.z, bv3.z, fmaf(a0.w, bv3.w, acc[0][3]))));
      acc[1][0] = fmaf(a1.x, bv0.x, fmaf(a1.y, bv0.y, fmaf(a1.z, bv0.z, fmaf(a1.w, bv0.w, acc[1][0]))));
      acc[1][1] = fmaf(a1.x, bv1.x, fmaf(a1.y, bv1.y, fmaf(a1.z, bv1.z, fmaf(a1.w, bv1.w, acc[1][1]))));
      acc[1][2] = fmaf(a1.x, bv2.x, fmaf(a1.y, bv2.y, fmaf(a1.z, bv2.z, fmaf(a1.w, bv2.w, acc[1][2]))));
      acc[1][3] = fmaf(a1.x, bv3.x, fmaf(a1.y, bv3.y, fmaf(a1.z, bv3.z, fmaf(a1.w, bv3.w, acc[1][3]))));
    }
  }

  const int hcol = hcol0 + tx;
#pragma unroll
  for (int r = 0; r < 2; ++r) {  // fused cell epilogue
    const int row = row0 + ty + 32 * r;
    const float u = g_u[ub][row];
    const float iv = acc[r][0] + u * s_wi[0 * 16 + tx] + s_bi[0 * 16 + tx];
    const float fv = acc[r][1] + u * s_wi[1 * 16 + tx] + s_bi[1 * 16 + tx];
    const float gv = acc[r][2] + u * s_wi[2 * 16 + tx] + s_bi[2 * 16 + tx];
    const float ov = acc[r][3] + u * s_wi[3 * 16 + tx] + s_bi[3 * 16 + tx];
    float c = g_C0[row][hcol];
    g_H0[nxt][row][hcol] = cellupd(iv, fv, gv, ov, c);
    g_C0[row][hcol] = c;
  }
  if (CG == 0 && tx == 0) {  // init next-u and out[:,d] with b_out
    const float bo = b_out[0];
#pragma unroll
    for (int r = 0; r < 2; ++r) {
      const int row = row0 + ty + 32 * r;
      g_u[nb][row] = bo;
      out[row * HOR + d] = bo;
    }
  }
}

__global__ __launch_bounds__(512, 4) void dec_l1(
    const float* __restrict__ w_ih1, const float* __restrict__ w_hh1,
    const float* __restrict__ b1, const float* __restrict__ w_out,
    float* __restrict__ out, int d) {
  __shared__ __align__(16) float As[DM][LSTR];
  __shared__ __align__(16) float Bs[DN][LSTR];
  __shared__ float s_bi[DN];
  const int tid = threadIdx.x;
  const int CG = blockIdx.x & 31, RQ = blockIdx.x >> 5;
  const int row0 = RQ * DM;
  const int hcol0 = CG * 16;
  const int tx = tid & 15, ty = tid >> 4;

  if (tid < DN) {
    const int jsrc = (tid >> 4) * HH + hcol0 + (tid & 15);
    s_bi[tid] = b1[jsrc];
  }

  const int cur = d & 1, nxt = cur ^ 1;
  const int nb = (d & 1) ^ 1;
  const int hcol = hcol0 + tx;
  const float wo = w_out[hcol];

  float acc[2][4];
#pragma unroll
  for (int r = 0; r < 2; ++r)
#pragma unroll
    for (int c = 0; c < 4; ++c) acc[r][c] = 0.f;

#pragma unroll
  for (int ph = 0; ph < 2; ++ph) {
    const float* __restrict__ A = ph ? &g_H1[cur][0][0] : &g_H0[nxt][0][0];
    const float* __restrict__ W = ph ? w_hh1 : w_ih1;
    for (int kt = 0; kt < 8; ++kt) {
      const int k0 = kt * DK;
      __syncthreads();
#pragma unroll
      for (int i = 0; i < 2; ++i) {
        const int q = tid + i * 512;
        const int m = q >> 4, kk = (q & 15) * 4;
        *(float4*)&As[m][kk] = *(const float4*)&A[(row0 + m) * HH + k0 + kk];
      }
#pragma unroll
      for (int i = 0; i < 2; ++i) {
        const int q = tid + i * 512;
        const int j = q >> 4, kk = (q & 15) * 4;
        const int jsrc = (j >> 4) * HH + hcol0 + (j & 15);
        *(float4*)&Bs[j][kk] = *(const float4*)&W[jsrc * HH + k0 + kk];
      }
      __syncthreads();
#pragma unroll 4
      for (int kc = 0; kc < 16; ++kc) {
        const float4 a0 = *(const float4*)&As[ty][kc * 4];
        const float4 a1 = *(const float4*)&As[ty + 32][kc * 4];
        const float4 bv0 = *(const float4*)&Bs[tx][kc * 4];
        const float4 bv1 = *(const float4*)&Bs[tx + 16][kc * 4];
        const float4 bv2 = *(const float4*)&Bs[tx + 32][kc * 4];
        const float4 bv3 = *(const float4*)&Bs[tx + 48][kc * 4];
        acc[0][0] = fmaf(a0.x, bv0.x, fmaf(a0.y, bv0.y, fmaf(a0.z, bv0.z, fmaf(a0.w, bv0.w, acc[0][0]))));
        acc[0][1] = fmaf(a0.x, bv1.x, fmaf(a0.y, bv1.y, fmaf(a0.z, bv1.z, fmaf(a0.w, bv1.w, acc[0][1]))));
        acc[0][2] = fmaf(a0.x, bv2.x, fmaf(a0.y, bv2.y, fmaf(a0.z, bv2.z, fmaf(a0.w, bv2.w, acc[0][2]))));
        acc[0][3] = fmaf(a0.x, bv3.x, fmaf(a0.y, bv3.y, fmaf(a0.z, bv3.z, fmaf(a0.w, bv3.w, acc[0][3]))));
        acc[1][0] = fmaf(a1.x, bv0.x, fmaf(a1.y, bv0.y, fmaf(a1.z, bv0.z, fmaf(a1.w, bv0.w, acc[1][0]))));
        acc[1][1] = fmaf(a1.x, bv1.x, fmaf(a1.y, bv1.y, fmaf(a1.z, bv1.z, fmaf(a1.w, bv1.w, acc[1][1]))));
        acc[1][2] = fmaf(a1.x, bv2.x, fmaf(a1.y, bv2.y, fmaf(a1.z, bv2.z, fmaf(a1.w, bv2.w, acc[1][2]))));
        acc[1][3] = fmaf(a1.x, bv3.x, fmaf(a1.y, bv3.y, fmaf(a1.z, bv3.z, fmaf(a1.w, bv3.w, acc[1][3]))));
      }
    }
  }

  float pp[2];
#pragma unroll
  for (int r = 0; r < 2; ++r) {  // fused cell epilogue + pred partial
    const int row = row0 + ty + 32 * r;
    const float iv = acc[r][0] + s_bi[0 * 16 + tx];
    const float fv = acc[r][1] + s_bi[1 * 16 + tx];
    const float gv = acc[r][2] + s_bi[2 * 16 + tx];
    const float ov = acc[r][3] + s_bi[3 * 16 + tx];
    float c = g_C1[row][hcol];
    const float h = cellupd(iv, fv, gv, ov, c);
    g_H1[nxt][row][hcol] = h;
    g_C1[row][hcol] = c;
    pp[r] = h * wo;
  }
  // reduce pred partials across the 16 hcol lanes (tx = lane&15)
#pragma unroll
  for (int off = 1; off < 16; off <<= 1) {
    pp[0] += __shfl_xor(pp[0], off);
    pp[1] += __shfl_xor(pp[1], off);
  }
  if (tx == 0) {
#pragma unroll
    for (int r = 0; r < 2; ++r) {
      const int row = row0 + ty + 32 * r;
      atomicAdd(&g_u[nb][row], pp[r]);
      atomicAdd(&out[row * HOR + d], pp[r]);
    }
  }
}

extern "C" void kernel_launch(void* const* d_in, const int* in_sizes, int n_in,
                              void* d_out, int out_size, void* d_ws, size_t ws_size,
                              hipStream_t stream) {
  (void)in_sizes; (void)n_in; (void)out_size; (void)ws_size;
  const float* x = (const float*)d_in[0];
  const float* init_input = (const float*)d_in[1];
  const float* w_ih0 = (const float*)d_in[2];
  const float* w_hh0 = (const float*)d_in[3];
  const float* b0 = (const float*)d_in[4];
  const float* w_ih1 = (const float*)d_in[5];
  const float* w_hh1 = (const float*)d_in[6];
  const float* b1 = (const float*)d_in[7];
  const float* w_out = (const float*)d_in[8];
  const float* b_out = (const float*)d_in[9];
  float* out = (float*)d_out;

  hipMemsetAsync(d_ws, 0, (ENW * 32 + 64) * sizeof(unsigned), stream);
  enc_kernel<<<ENW, ENT, 0, stream>>>(x, init_input, w_ih0, w_hh0, b0,
                                      w_ih1, w_hh1, b1, (unsigned*)d_ws);
  for (int d = 0; d < HOR; ++d) {
    dec_l0<<<512, 512, 0, stream>>>(w_hh0, w_ih0, b0, b_out, out, d);
    dec_l1<<<512, 512, 0, stream>>>(w_ih1, w_hh1, b1, w_out, out, d);
  }
}